// Round 7
// baseline (373.333 us; speedup 1.0000x reference)
//
#include <hip/hip_runtime.h>

#define N_NODES 50000
#define HALF_N  25000
#define E_EDGES 800000
#define CIN     32
#define COUT    64
#define NB2     32       // (half, cell) buckets
#define KPAD    136      // 128 bf16 + 8 pad
#define SCANB   1024
#define NSCANBLK ((N_NODES + SCANB - 1) / SCANB)   // 49
#define MSGCAP  500000   // per-half msg slots (actual ~400K +- 0.5K)

typedef __attribute__((ext_vector_type(8))) short s8v;   // 8 bf16 = 4 VGPRs
typedef __attribute__((ext_vector_type(4))) float f4v;

static __device__ inline unsigned short f2bf(float f) {  // RTNE fp32->bf16
    unsigned u = __builtin_bit_cast(unsigned, f);
    u += 0x7fff + ((u >> 16) & 1);
    return (unsigned short)(u >> 16);
}
static __device__ inline float bf2f(unsigned short h) {
    unsigned u = ((unsigned)h) << 16;
    return __builtin_bit_cast(float, u);
}

// ================= main (record/CSR) path =================

// pass A: (half,cell) histogram + integer degree count
__global__ __launch_bounds__(256) void count32(
    const int* __restrict__ ei, const float* __restrict__ pseudo,
    int* __restrict__ hist, int* __restrict__ degi)
{
    __shared__ int lh[NB2];
    if (threadIdx.x < NB2) lh[threadIdx.x] = 0;
    __syncthreads();
    const int e = blockIdx.x * 256 + threadIdx.x;
    if (e < E_EDGES) {
        int row = min(max(ei[e], 0), N_NODES - 1);
        const float v0 = pseudo[2 * e] * 4.0f, v1 = pseudo[2 * e + 1] * 4.0f;
        const int lo0 = min(max((int)floorf(v0), 0), 3);
        const int lo1 = min(max((int)floorf(v1), 0), 3);
        const int half = (row >= HALF_N) ? 1 : 0;
        atomicAdd(&lh[half * 16 + lo0 + 4 * lo1], 1);
        atomicAdd(&degi[row], 1);
    }
    __syncthreads();
    if (threadIdx.x < NB2) atomicAdd(&hist[threadIdx.x], lh[threadIdx.x]);
}

// pass B1: per-block local exclusive scan of degi
__global__ __launch_bounds__(1024) void scan_blocks(
    const int* __restrict__ degi, int* __restrict__ rowstart, int* __restrict__ bsum)
{
    __shared__ int wsum[16];
    __shared__ int woff[16];
    const int tid = threadIdx.x, lane = tid & 63, wid = tid >> 6;
    const int n = blockIdx.x * SCANB + tid;
    const int v = (n < N_NODES) ? degi[n] : 0;
    int val = v;
#pragma unroll
    for (int off = 1; off < 64; off <<= 1) {
        int t = __shfl_up(val, off);
        if (lane >= off) val += t;
    }
    if (lane == 63) wsum[wid] = val;
    __syncthreads();
    if (tid == 0) {
        int a = 0;
#pragma unroll
        for (int w = 0; w < 16; ++w) { woff[w] = a; a += wsum[w]; }
        bsum[blockIdx.x] = a;
    }
    __syncthreads();
    if (n < N_NODES) rowstart[n] = woff[wid] + (val - v);
}

// pass B2: scan 49 block sums + 32-bucket scan (tiny)
__global__ void scan_tops(const int* __restrict__ hist, int* __restrict__ bstart,
                          int* __restrict__ cursor, const int* __restrict__ bsum,
                          int* __restrict__ boffs, int* __restrict__ rowstart)
{
    if (threadIdx.x == 0 && blockIdx.x == 0) {
        int acc = 0;
        for (int c = 0; c < NB2; ++c) { bstart[c] = acc; cursor[c] = acc; acc += hist[c]; }
        int a = 0;
        for (int b = 0; b < NSCANBLK; ++b) { boffs[b] = a; a += bsum[b]; }
        rowstart[N_NODES] = a;
    }
}

// pass B3: add block offsets
__global__ __launch_bounds__(1024) void scan_add(
    int* __restrict__ rowstart, const int* __restrict__ boffs)
{
    const int n = blockIdx.x * SCANB + threadIdx.x;
    if (n < N_NODES && blockIdx.x > 0) rowstart[n] += boffs[blockIdx.x];
}

// pass C: scatter packed 8B records into (half,cell)-sorted list
// rec = row:16 | col:16 | f0q:16 | f1q:16
__global__ __launch_bounds__(256) void scatter32(
    const int* __restrict__ ei, const float* __restrict__ pseudo,
    int* __restrict__ cursor, unsigned long long* __restrict__ recs)
{
    __shared__ int lh[NB2];
    __shared__ int lbase[NB2];
    if (threadIdx.x < NB2) lh[threadIdx.x] = 0;
    __syncthreads();
    const int e = blockIdx.x * 256 + threadIdx.x;
    int b = 0, myoff = 0;
    unsigned long long rec = 0;
    if (e < E_EDGES) {
        const int row = min(max(ei[e], 0), N_NODES - 1);
        const int col = min(max(ei[E_EDGES + e], 0), N_NODES - 1);
        const float v0 = pseudo[2 * e] * 4.0f, v1 = pseudo[2 * e + 1] * 4.0f;
        const float fl0 = floorf(v0), fl1 = floorf(v1);
        const int lo0 = min(max((int)fl0, 0), 3);
        const int lo1 = min(max((int)fl1, 0), 3);
        const int f0q = min((int)((v0 - fl0) * 65536.0f), 65535);
        const int f1q = min((int)((v1 - fl1) * 65536.0f), 65535);
        const int half = (row >= HALF_N) ? 1 : 0;
        b = half * 16 + lo0 + 4 * lo1;
        rec = (unsigned long long)row
            | ((unsigned long long)col << 16)
            | ((unsigned long long)f0q << 32)
            | ((unsigned long long)f1q << 48);
        myoff = atomicAdd(&lh[b], 1);
    }
    __syncthreads();
    if (threadIdx.x < NB2)
        lbase[threadIdx.x] = atomicAdd(&cursor[threadIdx.x], lh[threadIdx.x]);
    __syncthreads();
    if (e < E_EDGES)
        recs[lbase[b] + myoff] = rec;
}

// pass D: per-(half,cell) MFMA; metadata from sequential records;
// basis pre-scaled by 1/deg; msg written to row-sorted slot (per-half buffer)
__global__ __launch_bounds__(256, 2) void bucket_mfma_rec(
    const float* __restrict__ x, const float* __restrict__ weight,
    const unsigned long long* __restrict__ recs,
    const int* __restrict__ bstart, const int* __restrict__ hist,
    const int* __restrict__ rowstart, int* __restrict__ rcur,
    unsigned short* __restrict__ msg, int h)
{
    __shared__ short XS[4][16 * KPAD];

    const int lane = threadIdx.x & 63;
    const int wid  = threadIdx.x >> 6;
    const int cell = blockIdx.x & 15;
    const int beta = h * 16 + cell;
    const int wGlob   = (blockIdx.x >> 4) * 4 + wid;
    const int wStride = (gridDim.x >> 4) * 4;

    const int lo0 = cell & 3, lo1 = cell >> 2;
    const int base = lo0 + 5 * lo1;
    const int offs[4] = {0, 1, 5, 6};
    const int q = lane >> 4;
    const int c = lane & 15;
    const int hbase = rowstart[h * HALF_N];   // uniform

    // B-fragments: Wstack[k=s*32+q*8+j][o=nt*16+c]
    s8v bfr[4][4];
#pragma unroll
    for (int s = 0; s < 4; ++s) {
        const float* wp = weight + (size_t)(base + offs[s]) * (CIN * COUT);
#pragma unroll
        for (int nt = 0; nt < 4; ++nt) {
            union { unsigned short u[8]; s8v v; } tmp;
#pragma unroll
            for (int j = 0; j < 8; ++j)
                tmp.u[j] = f2bf(wp[(q * 8 + j) * COUT + nt * 16 + c]);
            bfr[s][nt] = tmp.v;
        }
    }

    const int start  = bstart[beta];
    const int cnt    = hist[beta];
    const int ntiles = (cnt + 15) >> 4;

    for (int t = wGlob; t < ntiles; t += wStride) {
        const int ebase = start + t * 16;

        int colv = 0, slotv = 0;
        float b0 = 0.f, b1 = 0.f, b2 = 0.f, b3 = 0.f;
        if (lane < 16 && (t * 16 + lane) < cnt) {
            const unsigned long long rec = recs[ebase + lane];   // sequential
            const int row = (int)(rec & 0xFFFF);
            colv = (int)((rec >> 16) & 0xFFFF);
            const float f0 = (float)(int)((rec >> 32) & 0xFFFF) * (1.0f / 65536.0f);
            const float f1 = (float)(int)((rec >> 48) & 0xFFFF) * (1.0f / 65536.0f);
            const int rs = rowstart[row], re = rowstart[row + 1];   // L2-resident
            const float invd = 1.0f / (float)max(re - rs, 1);
            b0 = (1.0f - f0) * (1.0f - f1) * invd;
            b1 = f0 * (1.0f - f1) * invd;
            b2 = (1.0f - f0) * f1 * invd;
            b3 = f0 * f1 * invd;
            slotv = rs - hbase + atomicAdd(&rcur[row], 1);
        }

        // gather + scale + stage X' (16 x 128 bf16)
        {
            const int eg = lane >> 2, part = lane & 3;
            const int  gc = __shfl(colv, eg);
            const float ss0 = __shfl(b0, eg), ss1 = __shfl(b1, eg);
            const float ss2 = __shfl(b2, eg), ss3 = __shfl(b3, eg);
            const float ss[4] = {ss0, ss1, ss2, ss3};
            const float* xp = x + (size_t)gc * CIN + part * 8;
            float xv[8];
            *(f4v*)&xv[0] = *(const f4v*)xp;
            *(f4v*)&xv[4] = *(const f4v*)(xp + 4);
            short* dst = &XS[wid][eg * KPAD + part * 8];
#pragma unroll
            for (int s = 0; s < 4; ++s) {
                union { unsigned short u[8]; s8v v; } tmp;
#pragma unroll
                for (int j = 0; j < 8; ++j)
                    tmp.u[j] = f2bf(ss[s] * xv[j]);
                *(s8v*)(dst + s * 32) = tmp.v;
            }
        }
        __builtin_amdgcn_wave_barrier();

        s8v afr[4];
        {
            const short* ap = &XS[wid][c * KPAD + q * 8];
#pragma unroll
            for (int ks = 0; ks < 4; ++ks)
                afr[ks] = *(const s8v*)(ap + ks * 32);
        }
        __builtin_amdgcn_wave_barrier();

        f4v acc[4];
#pragma unroll
        for (int nt = 0; nt < 4; ++nt) {
            acc[nt] = (f4v){0.f, 0.f, 0.f, 0.f};
#pragma unroll
            for (int ks = 0; ks < 4; ++ks)
                acc[nt] = __builtin_amdgcn_mfma_f32_16x16x32_bf16(
                    afr[ks], bfr[ks][nt], acc[nt], 0, 0, 0);
        }

        // epilogue: acc -> bf16 tile in LDS, coalesced 128B store per edge
#pragma unroll
        for (int r = 0; r < 4; ++r) {
            const int m = q * 4 + r;
#pragma unroll
            for (int nt = 0; nt < 4; ++nt)
                XS[wid][m * 64 + nt * 16 + c] = (short)f2bf(acc[nt][r]);
        }
        __builtin_amdgcn_wave_barrier();
        {
            const int m2 = lane >> 2;
            int slot2 = __shfl(slotv, m2);
            const bool valid2 = (t * 16 + m2) < cnt;
            slot2 = min(slot2, MSGCAP - 1);   // defensive
            const short* sp = &XS[wid][lane * 16];
            s8v vlo = *(const s8v*)sp;
            s8v vhi = *(const s8v*)(sp + 8);
            if (valid2) {
                unsigned short* dst = msg + (size_t)slot2 * COUT + (lane & 3) * 16;
                *(s8v*)dst = vlo;
                *(s8v*)(dst + 8) = vhi;
            }
        }
        __builtin_amdgcn_wave_barrier();
    }
}

// pass E: per-node segment sum (msg pre-scaled by 1/deg) + root/bias fuse
__global__ __launch_bounds__(256) void gather_sum(
    const unsigned short* __restrict__ msg, const int* __restrict__ rowstart,
    const float* __restrict__ x, const float* __restrict__ root,
    const float* __restrict__ bias, float* __restrict__ out, int nstart)
{
    const int wave   = (blockIdx.x * blockDim.x + threadIdx.x) >> 6;
    const int lane   = threadIdx.x & 63;
    const int nwaves = (gridDim.x * blockDim.x) >> 6;
    const int hbase  = rowstart[nstart];

    for (int nn = wave; nn < HALF_N; nn += nwaves) {
        const int n  = nstart + nn;
        const int s  = rowstart[n] - hbase;
        const int e2 = rowstart[n + 1] - hbase;
        float acc = 0.f;
#pragma unroll 4
        for (int p = s; p < e2; ++p)
            acc += bf2f(msg[(size_t)p * COUT + lane]);
        const float* xp = x + (size_t)n * CIN;
        float rt = bias[lane];
#pragma unroll
        for (int i = 0; i < CIN; ++i)
            rt += xp[i] * root[i * COUT + lane];
        out[(size_t)n * COUT + lane] = acc + rt;
    }
}

// ================= fallback (R4 atomic) path =================

__global__ __launch_bounds__(256) void count_fb(
    const int* __restrict__ ei, const float* __restrict__ pseudo,
    int* __restrict__ hist, float* __restrict__ deg)
{
    __shared__ int lh[16];
    if (threadIdx.x < 16) lh[threadIdx.x] = 0;
    __syncthreads();
    const int e = blockIdx.x * 256 + threadIdx.x;
    if (e < E_EDGES) {
        int row = min(max(ei[e], 0), N_NODES - 1);
        const float v0 = pseudo[2 * e] * 4.0f, v1 = pseudo[2 * e + 1] * 4.0f;
        const int lo0 = min(max((int)floorf(v0), 0), 3);
        const int lo1 = min(max((int)floorf(v1), 0), 3);
        atomicAdd(&lh[lo0 + 4 * lo1], 1);
        atomicAdd(&deg[row], 1.0f);
    }
    __syncthreads();
    if (threadIdx.x < 16) atomicAdd(&hist[threadIdx.x], lh[threadIdx.x]);
}

__global__ void scan16_fb(const int* __restrict__ hist,
                          int* __restrict__ bstart, int* __restrict__ cursor)
{
    if (threadIdx.x == 0 && blockIdx.x == 0) {
        int acc = 0;
        for (int c = 0; c < 16; ++c) { bstart[c] = acc; cursor[c] = acc; acc += hist[c]; }
    }
}

__global__ __launch_bounds__(256) void scatter_fb(
    const float* __restrict__ pseudo, int* __restrict__ cursor, int* __restrict__ list)
{
    __shared__ int lh[16];
    __shared__ int lbase[16];
    if (threadIdx.x < 16) lh[threadIdx.x] = 0;
    __syncthreads();
    const int e = blockIdx.x * 256 + threadIdx.x;
    int cell = 0, myoff = 0;
    if (e < E_EDGES) {
        const float v0 = pseudo[2 * e] * 4.0f, v1 = pseudo[2 * e + 1] * 4.0f;
        const int lo0 = min(max((int)floorf(v0), 0), 3);
        const int lo1 = min(max((int)floorf(v1), 0), 3);
        cell = lo0 + 4 * lo1;
        myoff = atomicAdd(&lh[cell], 1);
    }
    __syncthreads();
    if (threadIdx.x < 16)
        lbase[threadIdx.x] = atomicAdd(&cursor[threadIdx.x], lh[threadIdx.x]);
    __syncthreads();
    if (e < E_EDGES)
        list[lbase[cell] + myoff] = e;
}

__global__ __launch_bounds__(256, 2) void bucket_mfma_fb(
    const float* __restrict__ x, const int* __restrict__ ei,
    const float* __restrict__ pseudo, const float* __restrict__ weight,
    const int* __restrict__ list, const int* __restrict__ bstart,
    const int* __restrict__ hist, float* __restrict__ out)
{
    __shared__ short XS[4][16 * KPAD];
    const int lane = threadIdx.x & 63;
    const int wid  = threadIdx.x >> 6;
    const int beta = blockIdx.x & 15;
    const int wGlob   = (blockIdx.x >> 4) * 4 + wid;
    const int wStride = (gridDim.x >> 4) * 4;
    const int lo0 = beta & 3, lo1 = beta >> 2;
    const int base = lo0 + 5 * lo1;
    const int offs[4] = {0, 1, 5, 6};
    const int q = lane >> 4, c = lane & 15;

    s8v bfr[4][4];
#pragma unroll
    for (int s = 0; s < 4; ++s) {
        const float* wp = weight + (size_t)(base + offs[s]) * (CIN * COUT);
#pragma unroll
        for (int nt = 0; nt < 4; ++nt) {
            union { unsigned short u[8]; s8v v; } tmp;
#pragma unroll
            for (int j = 0; j < 8; ++j)
                tmp.u[j] = f2bf(wp[(q * 8 + j) * COUT + nt * 16 + c]);
            bfr[s][nt] = tmp.v;
        }
    }
    const int start = bstart[beta], cnt = hist[beta];
    const int ntiles = (cnt + 15) >> 4;

    for (int t = wGlob; t < ntiles; t += wStride) {
        const int ebase = start + t * 16;
        int rowv = 0, colv = 0;
        float b0 = 0.f, b1 = 0.f, b2 = 0.f, b3 = 0.f;
        if (lane < 16 && (t * 16 + lane) < cnt) {
            const int e = list[ebase + lane];
            rowv = min(max(ei[e], 0), N_NODES - 1);
            colv = min(max(ei[E_EDGES + e], 0), N_NODES - 1);
            const float v0 = pseudo[2 * e] * 4.0f, v1 = pseudo[2 * e + 1] * 4.0f;
            const float f0 = v0 - floorf(v0), f1 = v1 - floorf(v1);
            b0 = (1.0f - f0) * (1.0f - f1);
            b1 = f0 * (1.0f - f1);
            b2 = (1.0f - f0) * f1;
            b3 = f0 * f1;
        }
        {
            const int eg = lane >> 2, part = lane & 3;
            const int  gc = __shfl(colv, eg);
            const float ss0 = __shfl(b0, eg), ss1 = __shfl(b1, eg);
            const float ss2 = __shfl(b2, eg), ss3 = __shfl(b3, eg);
            const float ss[4] = {ss0, ss1, ss2, ss3};
            const float* xp = x + (size_t)gc * CIN + part * 8;
            float xv[8];
            *(f4v*)&xv[0] = *(const f4v*)xp;
            *(f4v*)&xv[4] = *(const f4v*)(xp + 4);
            short* dst = &XS[wid][eg * KPAD + part * 8];
#pragma unroll
            for (int s = 0; s < 4; ++s) {
                union { unsigned short u[8]; s8v v; } tmp;
#pragma unroll
                for (int j = 0; j < 8; ++j)
                    tmp.u[j] = f2bf(ss[s] * xv[j]);
                *(s8v*)(dst + s * 32) = tmp.v;
            }
        }
        __builtin_amdgcn_wave_barrier();
        s8v afr[4];
        {
            const short* ap = &XS[wid][c * KPAD + q * 8];
#pragma unroll
            for (int ks = 0; ks < 4; ++ks)
                afr[ks] = *(const s8v*)(ap + ks * 32);
        }
        __builtin_amdgcn_wave_barrier();
        f4v acc[4];
#pragma unroll
        for (int nt = 0; nt < 4; ++nt) {
            acc[nt] = (f4v){0.f, 0.f, 0.f, 0.f};
#pragma unroll
            for (int ks = 0; ks < 4; ++ks)
                acc[nt] = __builtin_amdgcn_mfma_f32_16x16x32_bf16(
                    afr[ks], bfr[ks][nt], acc[nt], 0, 0, 0);
        }
#pragma unroll
        for (int r = 0; r < 4; ++r) {
            const int m = q * 4 + r;
            const int orow = __shfl(rowv, m);
#pragma unroll
            for (int nt = 0; nt < 4; ++nt)
                atomicAdd(&out[(size_t)orow * COUT + nt * 16 + c], acc[nt][r]);
        }
    }
}

__global__ __launch_bounds__(256) void final_fb(
    const float* __restrict__ x, const float* __restrict__ root,
    const float* __restrict__ bias, const float* __restrict__ deg,
    float* __restrict__ out)
{
    const int wave   = (blockIdx.x * blockDim.x + threadIdx.x) >> 6;
    const int lane   = threadIdx.x & 63;
    const int nwaves = (gridDim.x * blockDim.x) >> 6;
    for (int n = wave; n < N_NODES; n += nwaves) {
        const float* xp = x + (size_t)n * CIN;
        float acc = bias[lane];
#pragma unroll
        for (int i = 0; i < CIN; ++i)
            acc += xp[i] * root[i * COUT + lane];
        float dg = deg[n];
        dg = dg > 1.0f ? dg : 1.0f;
        const size_t idx = (size_t)n * COUT + lane;
        out[idx] = out[idx] / dg + acc;
    }
}

extern "C" void kernel_launch(void* const* d_in, const int* in_sizes, int n_in,
                              void* d_out, int out_size, void* d_ws, size_t ws_size,
                              hipStream_t stream) {
    const float* x      = (const float*)d_in[0];
    const int*   ei     = (const int*)d_in[1];
    const float* pseudo = (const float*)d_in[2];
    const float* weight = (const float*)d_in[3];
    const float* root   = (const float*)d_in[4];
    const float* bias   = (const float*)d_in[5];
    float* out = (float*)d_out;

    // ws layout (int elements)
    int* wsI = (int*)d_ws;
    int* hist32   = wsI;                        // 32
    int* bstart32 = wsI + 32;                   // 32
    int* cursor32 = wsI + 64;                   // 32
    int* degi     = wsI + 96;                   // 50000
    int* rcur     = wsI + 50096;                // 50000
    int* rowstart = wsI + 100096;               // 50001 (+15 pad)
    int* bsum     = wsI + 150112;               // 64
    int* boffs    = wsI + 150176;               // 64
    // 150240 ints = 600,960 B; 8B-aligned for recs
    unsigned long long* recs = (unsigned long long*)(wsI + 150240);  // 6.4 MB
    unsigned short* msg = (unsigned short*)((char*)d_ws + 600960 + 6400000);
    const size_t needed = 600960 + 6400000 + (size_t)MSGCAP * COUT * 2;  // ~71 MB

    const int eblocks = (E_EDGES + 255) / 256;   // 3125

    if (ws_size >= needed) {
        hipMemsetAsync(d_ws, 0, (size_t)100096 * 4, stream);  // hist..rcur
        count32    <<<eblocks, 256, 0, stream>>>(ei, pseudo, hist32, degi);
        scan_blocks<<<NSCANBLK, 1024, 0, stream>>>(degi, rowstart, bsum);
        scan_tops  <<<1, 64, 0, stream>>>(hist32, bstart32, cursor32, bsum, boffs, rowstart);
        scan_add   <<<NSCANBLK, 1024, 0, stream>>>(rowstart, boffs);
        scatter32  <<<eblocks, 256, 0, stream>>>(ei, pseudo, cursor32, recs);
        for (int h = 0; h < 2; ++h) {
            bucket_mfma_rec<<<16 * 128, 256, 0, stream>>>(
                x, weight, recs, bstart32, hist32, rowstart, rcur, msg, h);
            gather_sum<<<256, 256, 0, stream>>>(
                msg, rowstart, x, root, bias, out, h * HALF_N);
        }
    } else {
        // R4 fallback layout
        char* w = (char*)d_ws;
        float* degF   = (float*)w;
        int*   histF  = (int*)(w + 200064);
        int*   bstF   = (int*)(w + 200128);
        int*   curF   = (int*)(w + 200192);
        int*   listF  = (int*)(w + 200256);

        hipMemsetAsync(out, 0, sizeof(float) * (size_t)N_NODES * COUT, stream);
        hipMemsetAsync(degF, 0, sizeof(float) * (size_t)N_NODES, stream);
        hipMemsetAsync(histF, 0, 192, stream);

        count_fb      <<<eblocks, 256, 0, stream>>>(ei, pseudo, histF, degF);
        scan16_fb     <<<1, 64, 0, stream>>>(histF, bstF, curF);
        scatter_fb    <<<eblocks, 256, 0, stream>>>(pseudo, curF, listF);
        bucket_mfma_fb<<<16 * 64, 256, 0, stream>>>(x, ei, pseudo, weight, listF,
                                                    bstF, histF, out);
        final_fb      <<<1024, 256, 0, stream>>>(x, root, bias, degF, out);
    }
}

// Round 8
// 286.108 us; speedup vs baseline: 1.3049x; 1.3049x over previous
//
#include <hip/hip_runtime.h>

#define N_NODES 50000
#define HALF_N  25000
#define E_EDGES 800000
#define CIN     32
#define COUT    64
#define NB2     32       // (half, cell) buckets
#define KPAD    136      // 128 bf16 + 8 pad
#define SCANB   1024
#define NSCANBLK ((N_NODES + SCANB - 1) / SCANB)   // 49
#define MSGCAP  500000   // per-half msg slots (actual ~400K +- 0.5K)

typedef __attribute__((ext_vector_type(8))) short s8v;   // 8 bf16 = 4 VGPRs
typedef __attribute__((ext_vector_type(4))) float f4v;

static __device__ inline unsigned short f2bf(float f) {  // RTNE fp32->bf16
    unsigned u = __builtin_bit_cast(unsigned, f);
    u += 0x7fff + ((u >> 16) & 1);
    return (unsigned short)(u >> 16);
}
static __device__ inline float bf2f(unsigned short h) {
    unsigned u = ((unsigned)h) << 16;
    return __builtin_bit_cast(float, u);
}

// ================= main (record/CSR) path =================

// pass A: (half,cell) histogram + integer degree count
__global__ __launch_bounds__(256) void count32(
    const int* __restrict__ ei, const float* __restrict__ pseudo,
    int* __restrict__ hist, int* __restrict__ degi)
{
    __shared__ int lh[NB2];
    if (threadIdx.x < NB2) lh[threadIdx.x] = 0;
    __syncthreads();
    const int e = blockIdx.x * 256 + threadIdx.x;
    if (e < E_EDGES) {
        int row = min(max(ei[e], 0), N_NODES - 1);
        const float v0 = pseudo[2 * e] * 4.0f, v1 = pseudo[2 * e + 1] * 4.0f;
        const int lo0 = min(max((int)floorf(v0), 0), 3);
        const int lo1 = min(max((int)floorf(v1), 0), 3);
        const int half = (row >= HALF_N) ? 1 : 0;
        atomicAdd(&lh[half * 16 + lo0 + 4 * lo1], 1);
        atomicAdd(&degi[row], 1);
    }
    __syncthreads();
    if (threadIdx.x < NB2) atomicAdd(&hist[threadIdx.x], lh[threadIdx.x]);
}

// pass B1: per-block local exclusive scan of degi
__global__ __launch_bounds__(1024) void scan_blocks(
    const int* __restrict__ degi, int* __restrict__ rowstart, int* __restrict__ bsum)
{
    __shared__ int wsum[16];
    __shared__ int woff[16];
    const int tid = threadIdx.x, lane = tid & 63, wid = tid >> 6;
    const int n = blockIdx.x * SCANB + tid;
    const int v = (n < N_NODES) ? degi[n] : 0;
    int val = v;
#pragma unroll
    for (int off = 1; off < 64; off <<= 1) {
        int t = __shfl_up(val, off);
        if (lane >= off) val += t;
    }
    if (lane == 63) wsum[wid] = val;
    __syncthreads();
    if (tid == 0) {
        int a = 0;
#pragma unroll
        for (int w = 0; w < 16; ++w) { woff[w] = a; a += wsum[w]; }
        bsum[blockIdx.x] = a;
    }
    __syncthreads();
    if (n < N_NODES) rowstart[n] = woff[wid] + (val - v);
}

// pass B2: scan 49 block sums + 32-bucket scan (tiny)
__global__ void scan_tops(const int* __restrict__ hist, int* __restrict__ bstart,
                          int* __restrict__ cursor, const int* __restrict__ bsum,
                          int* __restrict__ boffs, int* __restrict__ rowstart)
{
    if (threadIdx.x == 0 && blockIdx.x == 0) {
        int acc = 0;
        for (int c = 0; c < NB2; ++c) { bstart[c] = acc; cursor[c] = acc; acc += hist[c]; }
        int a = 0;
        for (int b = 0; b < NSCANBLK; ++b) { boffs[b] = a; a += bsum[b]; }
        rowstart[N_NODES] = a;
    }
}

// pass B3: add block offsets
__global__ __launch_bounds__(1024) void scan_add(
    int* __restrict__ rowstart, const int* __restrict__ boffs)
{
    const int n = blockIdx.x * SCANB + threadIdx.x;
    if (n < N_NODES && blockIdx.x > 0) rowstart[n] += boffs[blockIdx.x];
}

// pass C: scatter packed 8B records into (half,cell)-sorted list
// rec = row:16 | col:16 | f0q:16 | f1q:16
__global__ __launch_bounds__(256) void scatter32(
    const int* __restrict__ ei, const float* __restrict__ pseudo,
    int* __restrict__ cursor, unsigned long long* __restrict__ recs)
{
    __shared__ int lh[NB2];
    __shared__ int lbase[NB2];
    if (threadIdx.x < NB2) lh[threadIdx.x] = 0;
    __syncthreads();
    const int e = blockIdx.x * 256 + threadIdx.x;
    int b = 0, myoff = 0;
    unsigned long long rec = 0;
    if (e < E_EDGES) {
        const int row = min(max(ei[e], 0), N_NODES - 1);
        const int col = min(max(ei[E_EDGES + e], 0), N_NODES - 1);
        const float v0 = pseudo[2 * e] * 4.0f, v1 = pseudo[2 * e + 1] * 4.0f;
        const float fl0 = floorf(v0), fl1 = floorf(v1);
        const int lo0 = min(max((int)fl0, 0), 3);
        const int lo1 = min(max((int)fl1, 0), 3);
        const int f0q = min((int)((v0 - fl0) * 65536.0f), 65535);
        const int f1q = min((int)((v1 - fl1) * 65536.0f), 65535);
        const int half = (row >= HALF_N) ? 1 : 0;
        b = half * 16 + lo0 + 4 * lo1;
        rec = (unsigned long long)row
            | ((unsigned long long)col << 16)
            | ((unsigned long long)f0q << 32)
            | ((unsigned long long)f1q << 48);
        myoff = atomicAdd(&lh[b], 1);
    }
    __syncthreads();
    if (threadIdx.x < NB2)
        lbase[threadIdx.x] = atomicAdd(&cursor[threadIdx.x], lh[threadIdx.x]);
    __syncthreads();
    if (e < E_EDGES)
        recs[lbase[b] + myoff] = rec;
}

// pass D: per-(half,cell) MFMA; metadata from sequential records;
// basis pre-scaled by 1/deg; msg written to row-sorted slot (per-half buffer)
__global__ __launch_bounds__(256, 2) void bucket_mfma_rec(
    const float* __restrict__ x, const float* __restrict__ weight,
    const unsigned long long* __restrict__ recs,
    const int* __restrict__ bstart, const int* __restrict__ hist,
    const int* __restrict__ rowstart, int* __restrict__ rcur,
    unsigned short* __restrict__ msg, int h)
{
    __shared__ short XS[4][16 * KPAD];

    const int lane = threadIdx.x & 63;
    const int wid  = threadIdx.x >> 6;
    const int cell = blockIdx.x & 15;
    const int beta = h * 16 + cell;
    const int wGlob   = (blockIdx.x >> 4) * 4 + wid;
    const int wStride = (gridDim.x >> 4) * 4;

    const int lo0 = cell & 3, lo1 = cell >> 2;
    const int base = lo0 + 5 * lo1;
    const int offs[4] = {0, 1, 5, 6};
    const int q = lane >> 4;
    const int c = lane & 15;
    const int hbase = rowstart[h * HALF_N];   // uniform

    // B-fragments: Wstack[k=s*32+q*8+j][o=nt*16+c]
    s8v bfr[4][4];
#pragma unroll
    for (int s = 0; s < 4; ++s) {
        const float* wp = weight + (size_t)(base + offs[s]) * (CIN * COUT);
#pragma unroll
        for (int nt = 0; nt < 4; ++nt) {
            union { unsigned short u[8]; s8v v; } tmp;
#pragma unroll
            for (int j = 0; j < 8; ++j)
                tmp.u[j] = f2bf(wp[(q * 8 + j) * COUT + nt * 16 + c]);
            bfr[s][nt] = tmp.v;
        }
    }

    const int start  = bstart[beta];
    const int cnt    = hist[beta];
    const int ntiles = (cnt + 15) >> 4;

    for (int t = wGlob; t < ntiles; t += wStride) {
        const int ebase = start + t * 16;

        int colv = 0, slotv = 0;
        float b0 = 0.f, b1 = 0.f, b2 = 0.f, b3 = 0.f;
        if (lane < 16 && (t * 16 + lane) < cnt) {
            const unsigned long long rec = recs[ebase + lane];   // sequential
            const int row = (int)(rec & 0xFFFF);
            colv = (int)((rec >> 16) & 0xFFFF);
            const float f0 = (float)(int)((rec >> 32) & 0xFFFF) * (1.0f / 65536.0f);
            const float f1 = (float)(int)((rec >> 48) & 0xFFFF) * (1.0f / 65536.0f);
            const int rs = rowstart[row], re = rowstart[row + 1];   // L2-resident
            const float invd = 1.0f / (float)max(re - rs, 1);
            b0 = (1.0f - f0) * (1.0f - f1) * invd;
            b1 = f0 * (1.0f - f1) * invd;
            b2 = (1.0f - f0) * f1 * invd;
            b3 = f0 * f1 * invd;
            slotv = rs - hbase + atomicAdd(&rcur[row], 1);
        }

        // gather + scale + stage X' (16 x 128 bf16)
        {
            const int eg = lane >> 2, part = lane & 3;
            const int  gc = __shfl(colv, eg);
            const float ss0 = __shfl(b0, eg), ss1 = __shfl(b1, eg);
            const float ss2 = __shfl(b2, eg), ss3 = __shfl(b3, eg);
            const float ss[4] = {ss0, ss1, ss2, ss3};
            const float* xp = x + (size_t)gc * CIN + part * 8;
            float xv[8];
            *(f4v*)&xv[0] = *(const f4v*)xp;
            *(f4v*)&xv[4] = *(const f4v*)(xp + 4);
            short* dst = &XS[wid][eg * KPAD + part * 8];
#pragma unroll
            for (int s = 0; s < 4; ++s) {
                union { unsigned short u[8]; s8v v; } tmp;
#pragma unroll
                for (int j = 0; j < 8; ++j)
                    tmp.u[j] = f2bf(ss[s] * xv[j]);
                *(s8v*)(dst + s * 32) = tmp.v;
            }
        }
        __builtin_amdgcn_wave_barrier();

        s8v afr[4];
        {
            const short* ap = &XS[wid][c * KPAD + q * 8];
#pragma unroll
            for (int ks = 0; ks < 4; ++ks)
                afr[ks] = *(const s8v*)(ap + ks * 32);
        }
        __builtin_amdgcn_wave_barrier();

        f4v acc[4];
#pragma unroll
        for (int nt = 0; nt < 4; ++nt) {
            acc[nt] = (f4v){0.f, 0.f, 0.f, 0.f};
#pragma unroll
            for (int ks = 0; ks < 4; ++ks)
                acc[nt] = __builtin_amdgcn_mfma_f32_16x16x32_bf16(
                    afr[ks], bfr[ks][nt], acc[nt], 0, 0, 0);
        }

        // epilogue: acc -> bf16 tile in LDS, coalesced 128B store per edge
#pragma unroll
        for (int r = 0; r < 4; ++r) {
            const int m = q * 4 + r;
#pragma unroll
            for (int nt = 0; nt < 4; ++nt)
                XS[wid][m * 64 + nt * 16 + c] = (short)f2bf(acc[nt][r]);
        }
        __builtin_amdgcn_wave_barrier();
        {
            const int m2 = lane >> 2;
            int slot2 = __shfl(slotv, m2);
            const bool valid2 = (t * 16 + m2) < cnt;
            slot2 = min(slot2, MSGCAP - 1);   // defensive
            const short* sp = &XS[wid][lane * 16];
            s8v vlo = *(const s8v*)sp;
            s8v vhi = *(const s8v*)(sp + 8);
            if (valid2) {
                unsigned short* dst = msg + (size_t)slot2 * COUT + (lane & 3) * 16;
                *(s8v*)dst = vlo;
                *(s8v*)(dst + 8) = vhi;
            }
        }
        __builtin_amdgcn_wave_barrier();
    }
}

// pass E: per-node segment sum (msg pre-scaled by 1/deg) + root/bias fuse
__global__ __launch_bounds__(256) void gather_sum(
    const unsigned short* __restrict__ msg, const int* __restrict__ rowstart,
    const float* __restrict__ x, const float* __restrict__ root,
    const float* __restrict__ bias, float* __restrict__ out, int nstart)
{
    const int wave   = (blockIdx.x * blockDim.x + threadIdx.x) >> 6;
    const int lane   = threadIdx.x & 63;
    const int nwaves = (gridDim.x * blockDim.x) >> 6;
    const int hbase  = rowstart[nstart];

    for (int nn = wave; nn < HALF_N; nn += nwaves) {
        const int n  = nstart + nn;
        const int s  = rowstart[n] - hbase;
        const int e2 = rowstart[n + 1] - hbase;
        float acc = 0.f;
#pragma unroll 8
        for (int p = s; p < e2; ++p)
            acc += bf2f(msg[(size_t)p * COUT + lane]);
        const float* xp = x + (size_t)n * CIN;
        float rt = bias[lane];
#pragma unroll
        for (int i = 0; i < CIN; ++i)
            rt += xp[i] * root[i * COUT + lane];
        out[(size_t)n * COUT + lane] = acc + rt;
    }
}

// ================= fallback (R4 atomic) path =================

__global__ __launch_bounds__(256) void count_fb(
    const int* __restrict__ ei, const float* __restrict__ pseudo,
    int* __restrict__ hist, float* __restrict__ deg)
{
    __shared__ int lh[16];
    if (threadIdx.x < 16) lh[threadIdx.x] = 0;
    __syncthreads();
    const int e = blockIdx.x * 256 + threadIdx.x;
    if (e < E_EDGES) {
        int row = min(max(ei[e], 0), N_NODES - 1);
        const float v0 = pseudo[2 * e] * 4.0f, v1 = pseudo[2 * e + 1] * 4.0f;
        const int lo0 = min(max((int)floorf(v0), 0), 3);
        const int lo1 = min(max((int)floorf(v1), 0), 3);
        atomicAdd(&lh[lo0 + 4 * lo1], 1);
        atomicAdd(&deg[row], 1.0f);
    }
    __syncthreads();
    if (threadIdx.x < 16) atomicAdd(&hist[threadIdx.x], lh[threadIdx.x]);
}

__global__ void scan16_fb(const int* __restrict__ hist,
                          int* __restrict__ bstart, int* __restrict__ cursor)
{
    if (threadIdx.x == 0 && blockIdx.x == 0) {
        int acc = 0;
        for (int c = 0; c < 16; ++c) { bstart[c] = acc; cursor[c] = acc; acc += hist[c]; }
    }
}

__global__ __launch_bounds__(256) void scatter_fb(
    const float* __restrict__ pseudo, int* __restrict__ cursor, int* __restrict__ list)
{
    __shared__ int lh[16];
    __shared__ int lbase[16];
    if (threadIdx.x < 16) lh[threadIdx.x] = 0;
    __syncthreads();
    const int e = blockIdx.x * 256 + threadIdx.x;
    int cell = 0, myoff = 0;
    if (e < E_EDGES) {
        const float v0 = pseudo[2 * e] * 4.0f, v1 = pseudo[2 * e + 1] * 4.0f;
        const int lo0 = min(max((int)floorf(v0), 0), 3);
        const int lo1 = min(max((int)floorf(v1), 0), 3);
        cell = lo0 + 4 * lo1;
        myoff = atomicAdd(&lh[cell], 1);
    }
    __syncthreads();
    if (threadIdx.x < 16)
        lbase[threadIdx.x] = atomicAdd(&cursor[threadIdx.x], lh[threadIdx.x]);
    __syncthreads();
    if (e < E_EDGES)
        list[lbase[cell] + myoff] = e;
}

__global__ __launch_bounds__(256, 2) void bucket_mfma_fb(
    const float* __restrict__ x, const int* __restrict__ ei,
    const float* __restrict__ pseudo, const float* __restrict__ weight,
    const int* __restrict__ list, const int* __restrict__ bstart,
    const int* __restrict__ hist, float* __restrict__ out)
{
    __shared__ short XS[4][16 * KPAD];
    const int lane = threadIdx.x & 63;
    const int wid  = threadIdx.x >> 6;
    const int beta = blockIdx.x & 15;
    const int wGlob   = (blockIdx.x >> 4) * 4 + wid;
    const int wStride = (gridDim.x >> 4) * 4;
    const int lo0 = beta & 3, lo1 = beta >> 2;
    const int base = lo0 + 5 * lo1;
    const int offs[4] = {0, 1, 5, 6};
    const int q = lane >> 4, c = lane & 15;

    s8v bfr[4][4];
#pragma unroll
    for (int s = 0; s < 4; ++s) {
        const float* wp = weight + (size_t)(base + offs[s]) * (CIN * COUT);
#pragma unroll
        for (int nt = 0; nt < 4; ++nt) {
            union { unsigned short u[8]; s8v v; } tmp;
#pragma unroll
            for (int j = 0; j < 8; ++j)
                tmp.u[j] = f2bf(wp[(q * 8 + j) * COUT + nt * 16 + c]);
            bfr[s][nt] = tmp.v;
        }
    }
    const int start = bstart[beta], cnt = hist[beta];
    const int ntiles = (cnt + 15) >> 4;

    for (int t = wGlob; t < ntiles; t += wStride) {
        const int ebase = start + t * 16;
        int rowv = 0, colv = 0;
        float b0 = 0.f, b1 = 0.f, b2 = 0.f, b3 = 0.f;
        if (lane < 16 && (t * 16 + lane) < cnt) {
            const int e = list[ebase + lane];
            rowv = min(max(ei[e], 0), N_NODES - 1);
            colv = min(max(ei[E_EDGES + e], 0), N_NODES - 1);
            const float v0 = pseudo[2 * e] * 4.0f, v1 = pseudo[2 * e + 1] * 4.0f;
            const float f0 = v0 - floorf(v0), f1 = v1 - floorf(v1);
            b0 = (1.0f - f0) * (1.0f - f1);
            b1 = f0 * (1.0f - f1);
            b2 = (1.0f - f0) * f1;
            b3 = f0 * f1;
        }
        {
            const int eg = lane >> 2, part = lane & 3;
            const int  gc = __shfl(colv, eg);
            const float ss0 = __shfl(b0, eg), ss1 = __shfl(b1, eg);
            const float ss2 = __shfl(b2, eg), ss3 = __shfl(b3, eg);
            const float ss[4] = {ss0, ss1, ss2, ss3};
            const float* xp = x + (size_t)gc * CIN + part * 8;
            float xv[8];
            *(f4v*)&xv[0] = *(const f4v*)xp;
            *(f4v*)&xv[4] = *(const f4v*)(xp + 4);
            short* dst = &XS[wid][eg * KPAD + part * 8];
#pragma unroll
            for (int s = 0; s < 4; ++s) {
                union { unsigned short u[8]; s8v v; } tmp;
#pragma unroll
                for (int j = 0; j < 8; ++j)
                    tmp.u[j] = f2bf(ss[s] * xv[j]);
                *(s8v*)(dst + s * 32) = tmp.v;
            }
        }
        __builtin_amdgcn_wave_barrier();
        s8v afr[4];
        {
            const short* ap = &XS[wid][c * KPAD + q * 8];
#pragma unroll
            for (int ks = 0; ks < 4; ++ks)
                afr[ks] = *(const s8v*)(ap + ks * 32);
        }
        __builtin_amdgcn_wave_barrier();
        f4v acc[4];
#pragma unroll
        for (int nt = 0; nt < 4; ++nt) {
            acc[nt] = (f4v){0.f, 0.f, 0.f, 0.f};
#pragma unroll
            for (int ks = 0; ks < 4; ++ks)
                acc[nt] = __builtin_amdgcn_mfma_f32_16x16x32_bf16(
                    afr[ks], bfr[ks][nt], acc[nt], 0, 0, 0);
        }
#pragma unroll
        for (int r = 0; r < 4; ++r) {
            const int m = q * 4 + r;
            const int orow = __shfl(rowv, m);
#pragma unroll
            for (int nt = 0; nt < 4; ++nt)
                atomicAdd(&out[(size_t)orow * COUT + nt * 16 + c], acc[nt][r]);
        }
    }
}

__global__ __launch_bounds__(256) void final_fb(
    const float* __restrict__ x, const float* __restrict__ root,
    const float* __restrict__ bias, const float* __restrict__ deg,
    float* __restrict__ out)
{
    const int wave   = (blockIdx.x * blockDim.x + threadIdx.x) >> 6;
    const int lane   = threadIdx.x & 63;
    const int nwaves = (gridDim.x * blockDim.x) >> 6;
    for (int n = wave; n < N_NODES; n += nwaves) {
        const float* xp = x + (size_t)n * CIN;
        float acc = bias[lane];
#pragma unroll
        for (int i = 0; i < CIN; ++i)
            acc += xp[i] * root[i * COUT + lane];
        float dg = deg[n];
        dg = dg > 1.0f ? dg : 1.0f;
        const size_t idx = (size_t)n * COUT + lane;
        out[idx] = out[idx] / dg + acc;
    }
}

extern "C" void kernel_launch(void* const* d_in, const int* in_sizes, int n_in,
                              void* d_out, int out_size, void* d_ws, size_t ws_size,
                              hipStream_t stream) {
    const float* x      = (const float*)d_in[0];
    const int*   ei     = (const int*)d_in[1];
    const float* pseudo = (const float*)d_in[2];
    const float* weight = (const float*)d_in[3];
    const float* root   = (const float*)d_in[4];
    const float* bias   = (const float*)d_in[5];
    float* out = (float*)d_out;

    // ws layout (int elements)
    int* wsI = (int*)d_ws;
    int* hist32   = wsI;                        // 32
    int* bstart32 = wsI + 32;                   // 32
    int* cursor32 = wsI + 64;                   // 32
    int* degi     = wsI + 96;                   // 50000
    int* rcur     = wsI + 50096;                // 50000
    int* rowstart = wsI + 100096;               // 50001 (+15 pad)
    int* bsum     = wsI + 150112;               // 64
    int* boffs    = wsI + 150176;               // 64
    // 150240 ints = 600,960 B; 8B-aligned for recs
    unsigned long long* recs = (unsigned long long*)(wsI + 150240);  // 6.4 MB
    unsigned short* msg = (unsigned short*)((char*)d_ws + 600960 + 6400000);
    const size_t needed = 600960 + 6400000 + (size_t)MSGCAP * COUT * 2;  // ~71 MB

    const int eblocks = (E_EDGES + 255) / 256;   // 3125

    if (ws_size >= needed) {
        hipMemsetAsync(d_ws, 0, (size_t)100096 * 4, stream);  // hist..rcur
        count32    <<<eblocks, 256, 0, stream>>>(ei, pseudo, hist32, degi);
        scan_blocks<<<NSCANBLK, 1024, 0, stream>>>(degi, rowstart, bsum);
        scan_tops  <<<1, 64, 0, stream>>>(hist32, bstart32, cursor32, bsum, boffs, rowstart);
        scan_add   <<<NSCANBLK, 1024, 0, stream>>>(rowstart, boffs);
        scatter32  <<<eblocks, 256, 0, stream>>>(ei, pseudo, cursor32, recs);
        for (int h = 0; h < 2; ++h) {
            bucket_mfma_rec<<<16 * 64, 256, 0, stream>>>(
                x, weight, recs, bstart32, hist32, rowstart, rcur, msg, h);
            gather_sum<<<2048, 256, 0, stream>>>(
                msg, rowstart, x, root, bias, out, h * HALF_N);
        }
    } else {
        // R4 fallback layout
        char* w = (char*)d_ws;
        float* degF   = (float*)w;
        int*   histF  = (int*)(w + 200064);
        int*   bstF   = (int*)(w + 200128);
        int*   curF   = (int*)(w + 200192);
        int*   listF  = (int*)(w + 200256);

        hipMemsetAsync(out, 0, sizeof(float) * (size_t)N_NODES * COUT, stream);
        hipMemsetAsync(degF, 0, sizeof(float) * (size_t)N_NODES, stream);
        hipMemsetAsync(histF, 0, 192, stream);

        count_fb      <<<eblocks, 256, 0, stream>>>(ei, pseudo, histF, degF);
        scan16_fb     <<<1, 64, 0, stream>>>(histF, bstF, curF);
        scatter_fb    <<<eblocks, 256, 0, stream>>>(pseudo, curF, listF);
        bucket_mfma_fb<<<16 * 64, 256, 0, stream>>>(x, ei, pseudo, weight, listF,
                                                    bstF, histF, out);
        final_fb      <<<1024, 256, 0, stream>>>(x, root, bias, degF, out);
    }
}

// Round 9
// 251.708 us; speedup vs baseline: 1.4832x; 1.1367x over previous
//
#include <hip/hip_runtime.h>

#define N_NODES 50000
#define HALF_N  25000
#define E_EDGES 800000
#define CIN     32
#define COUT    64
#define NB2     32       // (half, cell) buckets
#define BCAP    27008    // per-bucket record capacity (avg 25000, +10 sigma)
#define KPAD    136      // 128 bf16 + 8 pad
#define SCANB   1024
#define NSCANBLK ((N_NODES + SCANB - 1) / SCANB)   // 49
#define MSGCAP  500000   // per-half msg slots (actual ~400K)

typedef __attribute__((ext_vector_type(8))) short s8v;   // 8 bf16 = 4 VGPRs
typedef __attribute__((ext_vector_type(4))) float f4v;

static __device__ inline unsigned short f2bf(float f) {  // RTNE fp32->bf16
    unsigned u = __builtin_bit_cast(unsigned, f);
    u += 0x7fff + ((u >> 16) & 1);
    return (unsigned short)(u >> 16);
}
static __device__ inline float bf2f(unsigned short h) {
    unsigned u = ((unsigned)h) << 16;
    return __builtin_bit_cast(float, u);
}

// ================= main (record/CSR) path =================

// fused pass: build (half,cell)-bucketed 8B records + degree count.
// rec = row:16 | col:16 | f0q:16 | f1q:16. Fixed-capacity bucket regions
// (b*BCAP) remove the dependency on an exact bucket scan. The degi atomic
// is fire-and-forget; its L2 drain overlaps the record-write stream.
__global__ __launch_bounds__(256) void build_recs(
    const int* __restrict__ ei, const float* __restrict__ pseudo,
    int* __restrict__ cursor, unsigned long long* __restrict__ recs,
    int* __restrict__ degi)
{
    __shared__ int lh[NB2];
    __shared__ int lbase[NB2];
    if (threadIdx.x < NB2) lh[threadIdx.x] = 0;
    __syncthreads();
    const int e = blockIdx.x * 256 + threadIdx.x;
    int b = 0, myoff = 0;
    unsigned long long rec = 0;
    if (e < E_EDGES) {
        const int row = min(max(ei[e], 0), N_NODES - 1);
        const int col = min(max(ei[E_EDGES + e], 0), N_NODES - 1);
        const float v0 = pseudo[2 * e] * 4.0f, v1 = pseudo[2 * e + 1] * 4.0f;
        const float fl0 = floorf(v0), fl1 = floorf(v1);
        const int lo0 = min(max((int)fl0, 0), 3);
        const int lo1 = min(max((int)fl1, 0), 3);
        const int f0q = min((int)((v0 - fl0) * 65536.0f), 65535);
        const int f1q = min((int)((v1 - fl1) * 65536.0f), 65535);
        const int half = (row >= HALF_N) ? 1 : 0;
        b = half * 16 + lo0 + 4 * lo1;
        rec = (unsigned long long)row
            | ((unsigned long long)col << 16)
            | ((unsigned long long)f0q << 32)
            | ((unsigned long long)f1q << 48);
        myoff = atomicAdd(&lh[b], 1);
        atomicAdd(&degi[row], 1);            // result unused -> no wave stall
    }
    __syncthreads();
    if (threadIdx.x < NB2)
        lbase[threadIdx.x] = atomicAdd(&cursor[threadIdx.x], lh[threadIdx.x]);
    __syncthreads();
    if (e < E_EDGES) {
        const int idx = min(lbase[b] + myoff, BCAP - 1);   // defensive clamp
        recs[(size_t)b * BCAP + idx] = rec;
    }
}

// pass B1: per-block local exclusive scan of degi
__global__ __launch_bounds__(1024) void scan_blocks(
    const int* __restrict__ degi, int* __restrict__ rowstart, int* __restrict__ bsum)
{
    __shared__ int wsum[16];
    __shared__ int woff[16];
    const int tid = threadIdx.x, lane = tid & 63, wid = tid >> 6;
    const int n = blockIdx.x * SCANB + tid;
    const int v = (n < N_NODES) ? degi[n] : 0;
    int val = v;
#pragma unroll
    for (int off = 1; off < 64; off <<= 1) {
        int t = __shfl_up(val, off);
        if (lane >= off) val += t;
    }
    if (lane == 63) wsum[wid] = val;
    __syncthreads();
    if (tid == 0) {
        int a = 0;
#pragma unroll
        for (int w = 0; w < 16; ++w) { woff[w] = a; a += wsum[w]; }
        bsum[blockIdx.x] = a;
    }
    __syncthreads();
    if (n < N_NODES) rowstart[n] = woff[wid] + (val - v);
}

// pass B2: each block self-computes its bsum prefix and adds it
__global__ __launch_bounds__(1024) void scan_finish(
    int* __restrict__ rowstart, const int* __restrict__ bsum)
{
    const int b = blockIdx.x;
    int off = 0;
    for (int i = 0; i < NSCANBLK; ++i)          // 49 scalar loads, broadcast
        off += (i < b) ? bsum[i] : 0;
    const int n = b * SCANB + threadIdx.x;
    if (n < N_NODES) rowstart[n] += off;
    if (b == NSCANBLK - 1 && threadIdx.x == 0)
        rowstart[N_NODES] = off + bsum[NSCANBLK - 1];
}

// pass D: per-(half,cell) MFMA; metadata from sequential records;
// basis pre-scaled by 1/deg; msg written to row-sorted slot (per-half buffer)
__global__ __launch_bounds__(256, 2) void bucket_mfma_rec(
    const float* __restrict__ x, const float* __restrict__ weight,
    const unsigned long long* __restrict__ recs,
    const int* __restrict__ cursor,
    const int* __restrict__ rowstart, int* __restrict__ rcur,
    unsigned short* __restrict__ msg, int h)
{
    __shared__ short XS[4][16 * KPAD];

    const int lane = threadIdx.x & 63;
    const int wid  = threadIdx.x >> 6;
    const int cell = blockIdx.x & 15;
    const int beta = h * 16 + cell;
    const int wGlob   = (blockIdx.x >> 4) * 4 + wid;
    const int wStride = (gridDim.x >> 4) * 4;

    const int lo0 = cell & 3, lo1 = cell >> 2;
    const int base = lo0 + 5 * lo1;
    const int offs[4] = {0, 1, 5, 6};
    const int q = lane >> 4;
    const int c = lane & 15;
    const int hbase = rowstart[h * HALF_N];   // uniform

    // B-fragments: Wstack[k=s*32+q*8+j][o=nt*16+c]
    s8v bfr[4][4];
#pragma unroll
    for (int s = 0; s < 4; ++s) {
        const float* wp = weight + (size_t)(base + offs[s]) * (CIN * COUT);
#pragma unroll
        for (int nt = 0; nt < 4; ++nt) {
            union { unsigned short u[8]; s8v v; } tmp;
#pragma unroll
            for (int j = 0; j < 8; ++j)
                tmp.u[j] = f2bf(wp[(q * 8 + j) * COUT + nt * 16 + c]);
            bfr[s][nt] = tmp.v;
        }
    }

    const unsigned long long* brec = recs + (size_t)beta * BCAP;
    const int cnt    = min(cursor[beta], BCAP);
    const int ntiles = (cnt + 15) >> 4;

    for (int t = wGlob; t < ntiles; t += wStride) {
        const int ebase = t * 16;

        int colv = 0, slotv = 0;
        float b0 = 0.f, b1 = 0.f, b2 = 0.f, b3 = 0.f;
        if (lane < 16 && (ebase + lane) < cnt) {
            const unsigned long long rec = brec[ebase + lane];   // sequential
            const int row = (int)(rec & 0xFFFF);
            colv = (int)((rec >> 16) & 0xFFFF);
            const float f0 = (float)(int)((rec >> 32) & 0xFFFF) * (1.0f / 65536.0f);
            const float f1 = (float)(int)((rec >> 48) & 0xFFFF) * (1.0f / 65536.0f);
            const int rs = rowstart[row], re = rowstart[row + 1];   // L2-resident
            const float invd = 1.0f / (float)max(re - rs, 1);
            b0 = (1.0f - f0) * (1.0f - f1) * invd;
            b1 = f0 * (1.0f - f1) * invd;
            b2 = (1.0f - f0) * f1 * invd;
            b3 = f0 * f1 * invd;
            slotv = rs - hbase + atomicAdd(&rcur[row], 1);
        }

        // gather + scale + stage X' (16 x 128 bf16)
        {
            const int eg = lane >> 2, part = lane & 3;
            const int  gc = __shfl(colv, eg);
            const float ss0 = __shfl(b0, eg), ss1 = __shfl(b1, eg);
            const float ss2 = __shfl(b2, eg), ss3 = __shfl(b3, eg);
            const float ss[4] = {ss0, ss1, ss2, ss3};
            const float* xp = x + (size_t)gc * CIN + part * 8;
            float xv[8];
            *(f4v*)&xv[0] = *(const f4v*)xp;
            *(f4v*)&xv[4] = *(const f4v*)(xp + 4);
            short* dst = &XS[wid][eg * KPAD + part * 8];
#pragma unroll
            for (int s = 0; s < 4; ++s) {
                union { unsigned short u[8]; s8v v; } tmp;
#pragma unroll
                for (int j = 0; j < 8; ++j)
                    tmp.u[j] = f2bf(ss[s] * xv[j]);
                *(s8v*)(dst + s * 32) = tmp.v;
            }
        }
        __builtin_amdgcn_wave_barrier();

        s8v afr[4];
        {
            const short* ap = &XS[wid][c * KPAD + q * 8];
#pragma unroll
            for (int ks = 0; ks < 4; ++ks)
                afr[ks] = *(const s8v*)(ap + ks * 32);
        }
        __builtin_amdgcn_wave_barrier();

        f4v acc[4];
#pragma unroll
        for (int nt = 0; nt < 4; ++nt) {
            acc[nt] = (f4v){0.f, 0.f, 0.f, 0.f};
#pragma unroll
            for (int ks = 0; ks < 4; ++ks)
                acc[nt] = __builtin_amdgcn_mfma_f32_16x16x32_bf16(
                    afr[ks], bfr[ks][nt], acc[nt], 0, 0, 0);
        }

        // epilogue: acc -> bf16 tile in LDS, coalesced 128B store per edge
#pragma unroll
        for (int r = 0; r < 4; ++r) {
            const int m = q * 4 + r;
#pragma unroll
            for (int nt = 0; nt < 4; ++nt)
                XS[wid][m * 64 + nt * 16 + c] = (short)f2bf(acc[nt][r]);
        }
        __builtin_amdgcn_wave_barrier();
        {
            const int m2 = lane >> 2;
            int slot2 = __shfl(slotv, m2);
            const bool valid2 = (ebase + m2) < cnt;
            slot2 = min(slot2, MSGCAP - 1);   // defensive
            const short* sp = &XS[wid][lane * 16];
            s8v vlo = *(const s8v*)sp;
            s8v vhi = *(const s8v*)(sp + 8);
            if (valid2) {
                unsigned short* dst = msg + (size_t)slot2 * COUT + (lane & 3) * 16;
                *(s8v*)dst = vlo;
                *(s8v*)(dst + 8) = vhi;
            }
        }
        __builtin_amdgcn_wave_barrier();
    }
}

// pass E: per-node segment sum (msg pre-scaled by 1/deg) + root/bias fuse
__global__ __launch_bounds__(256) void gather_sum(
    const unsigned short* __restrict__ msg, const int* __restrict__ rowstart,
    const float* __restrict__ x, const float* __restrict__ root,
    const float* __restrict__ bias, float* __restrict__ out, int nstart)
{
    const int wave   = (blockIdx.x * blockDim.x + threadIdx.x) >> 6;
    const int lane   = threadIdx.x & 63;
    const int nwaves = (gridDim.x * blockDim.x) >> 6;
    const int hbase  = rowstart[nstart];

    for (int nn = wave; nn < HALF_N; nn += nwaves) {
        const int n  = nstart + nn;
        const int s  = rowstart[n] - hbase;
        const int e2 = rowstart[n + 1] - hbase;
        float acc = 0.f;
#pragma unroll 8
        for (int p = s; p < e2; ++p)
            acc += bf2f(msg[(size_t)p * COUT + lane]);
        const float* xp = x + (size_t)n * CIN;
        float rt = bias[lane];
#pragma unroll
        for (int i = 0; i < CIN; ++i)
            rt += xp[i] * root[i * COUT + lane];
        out[(size_t)n * COUT + lane] = acc + rt;
    }
}

// ================= fallback (R4 atomic) path =================

__global__ __launch_bounds__(256) void count_fb(
    const int* __restrict__ ei, const float* __restrict__ pseudo,
    int* __restrict__ hist, float* __restrict__ deg)
{
    __shared__ int lh[16];
    if (threadIdx.x < 16) lh[threadIdx.x] = 0;
    __syncthreads();
    const int e = blockIdx.x * 256 + threadIdx.x;
    if (e < E_EDGES) {
        int row = min(max(ei[e], 0), N_NODES - 1);
        const float v0 = pseudo[2 * e] * 4.0f, v1 = pseudo[2 * e + 1] * 4.0f;
        const int lo0 = min(max((int)floorf(v0), 0), 3);
        const int lo1 = min(max((int)floorf(v1), 0), 3);
        atomicAdd(&lh[lo0 + 4 * lo1], 1);
        atomicAdd(&deg[row], 1.0f);
    }
    __syncthreads();
    if (threadIdx.x < 16) atomicAdd(&hist[threadIdx.x], lh[threadIdx.x]);
}

__global__ void scan16_fb(const int* __restrict__ hist,
                          int* __restrict__ bstart, int* __restrict__ cursor)
{
    if (threadIdx.x == 0 && blockIdx.x == 0) {
        int acc = 0;
        for (int c = 0; c < 16; ++c) { bstart[c] = acc; cursor[c] = acc; acc += hist[c]; }
    }
}

__global__ __launch_bounds__(256) void scatter_fb(
    const float* __restrict__ pseudo, int* __restrict__ cursor, int* __restrict__ list)
{
    __shared__ int lh[16];
    __shared__ int lbase[16];
    if (threadIdx.x < 16) lh[threadIdx.x] = 0;
    __syncthreads();
    const int e = blockIdx.x * 256 + threadIdx.x;
    int cell = 0, myoff = 0;
    if (e < E_EDGES) {
        const float v0 = pseudo[2 * e] * 4.0f, v1 = pseudo[2 * e + 1] * 4.0f;
        const int lo0 = min(max((int)floorf(v0), 0), 3);
        const int lo1 = min(max((int)floorf(v1), 0), 3);
        cell = lo0 + 4 * lo1;
        myoff = atomicAdd(&lh[cell], 1);
    }
    __syncthreads();
    if (threadIdx.x < 16)
        lbase[threadIdx.x] = atomicAdd(&cursor[threadIdx.x], lh[threadIdx.x]);
    __syncthreads();
    if (e < E_EDGES)
        list[lbase[cell] + myoff] = e;
}

__global__ __launch_bounds__(256, 2) void bucket_mfma_fb(
    const float* __restrict__ x, const int* __restrict__ ei,
    const float* __restrict__ pseudo, const float* __restrict__ weight,
    const int* __restrict__ list, const int* __restrict__ bstart,
    const int* __restrict__ hist, float* __restrict__ out)
{
    __shared__ short XS[4][16 * KPAD];
    const int lane = threadIdx.x & 63;
    const int wid  = threadIdx.x >> 6;
    const int beta = blockIdx.x & 15;
    const int wGlob   = (blockIdx.x >> 4) * 4 + wid;
    const int wStride = (gridDim.x >> 4) * 4;
    const int lo0 = beta & 3, lo1 = beta >> 2;
    const int base = lo0 + 5 * lo1;
    const int offs[4] = {0, 1, 5, 6};
    const int q = lane >> 4, c = lane & 15;

    s8v bfr[4][4];
#pragma unroll
    for (int s = 0; s < 4; ++s) {
        const float* wp = weight + (size_t)(base + offs[s]) * (CIN * COUT);
#pragma unroll
        for (int nt = 0; nt < 4; ++nt) {
            union { unsigned short u[8]; s8v v; } tmp;
#pragma unroll
            for (int j = 0; j < 8; ++j)
                tmp.u[j] = f2bf(wp[(q * 8 + j) * COUT + nt * 16 + c]);
            bfr[s][nt] = tmp.v;
        }
    }
    const int start = bstart[beta], cnt = hist[beta];
    const int ntiles = (cnt + 15) >> 4;

    for (int t = wGlob; t < ntiles; t += wStride) {
        const int ebase = start + t * 16;
        int rowv = 0, colv = 0;
        float b0 = 0.f, b1 = 0.f, b2 = 0.f, b3 = 0.f;
        if (lane < 16 && (t * 16 + lane) < cnt) {
            const int e = list[ebase + lane];
            rowv = min(max(ei[e], 0), N_NODES - 1);
            colv = min(max(ei[E_EDGES + e], 0), N_NODES - 1);
            const float v0 = pseudo[2 * e] * 4.0f, v1 = pseudo[2 * e + 1] * 4.0f;
            const float f0 = v0 - floorf(v0), f1 = v1 - floorf(v1);
            b0 = (1.0f - f0) * (1.0f - f1);
            b1 = f0 * (1.0f - f1);
            b2 = (1.0f - f0) * f1;
            b3 = f0 * f1;
        }
        {
            const int eg = lane >> 2, part = lane & 3;
            const int  gc = __shfl(colv, eg);
            const float ss0 = __shfl(b0, eg), ss1 = __shfl(b1, eg);
            const float ss2 = __shfl(b2, eg), ss3 = __shfl(b3, eg);
            const float ss[4] = {ss0, ss1, ss2, ss3};
            const float* xp = x + (size_t)gc * CIN + part * 8;
            float xv[8];
            *(f4v*)&xv[0] = *(const f4v*)xp;
            *(f4v*)&xv[4] = *(const f4v*)(xp + 4);
            short* dst = &XS[wid][eg * KPAD + part * 8];
#pragma unroll
            for (int s = 0; s < 4; ++s) {
                union { unsigned short u[8]; s8v v; } tmp;
#pragma unroll
                for (int j = 0; j < 8; ++j)
                    tmp.u[j] = f2bf(ss[s] * xv[j]);
                *(s8v*)(dst + s * 32) = tmp.v;
            }
        }
        __builtin_amdgcn_wave_barrier();
        s8v afr[4];
        {
            const short* ap = &XS[wid][c * KPAD + q * 8];
#pragma unroll
            for (int ks = 0; ks < 4; ++ks)
                afr[ks] = *(const s8v*)(ap + ks * 32);
        }
        __builtin_amdgcn_wave_barrier();
        f4v acc[4];
#pragma unroll
        for (int nt = 0; nt < 4; ++nt) {
            acc[nt] = (f4v){0.f, 0.f, 0.f, 0.f};
#pragma unroll
            for (int ks = 0; ks < 4; ++ks)
                acc[nt] = __builtin_amdgcn_mfma_f32_16x16x32_bf16(
                    afr[ks], bfr[ks][nt], acc[nt], 0, 0, 0);
        }
#pragma unroll
        for (int r = 0; r < 4; ++r) {
            const int m = q * 4 + r;
            const int orow = __shfl(rowv, m);
#pragma unroll
            for (int nt = 0; nt < 4; ++nt)
                atomicAdd(&out[(size_t)orow * COUT + nt * 16 + c], acc[nt][r]);
        }
    }
}

__global__ __launch_bounds__(256) void final_fb(
    const float* __restrict__ x, const float* __restrict__ root,
    const float* __restrict__ bias, const float* __restrict__ deg,
    float* __restrict__ out)
{
    const int wave   = (blockIdx.x * blockDim.x + threadIdx.x) >> 6;
    const int lane   = threadIdx.x & 63;
    const int nwaves = (gridDim.x * blockDim.x) >> 6;
    for (int n = wave; n < N_NODES; n += nwaves) {
        const float* xp = x + (size_t)n * CIN;
        float acc = bias[lane];
#pragma unroll
        for (int i = 0; i < CIN; ++i)
            acc += xp[i] * root[i * COUT + lane];
        float dg = deg[n];
        dg = dg > 1.0f ? dg : 1.0f;
        const size_t idx = (size_t)n * COUT + lane;
        out[idx] = out[idx] / dg + acc;
    }
}

extern "C" void kernel_launch(void* const* d_in, const int* in_sizes, int n_in,
                              void* d_out, int out_size, void* d_ws, size_t ws_size,
                              hipStream_t stream) {
    const float* x      = (const float*)d_in[0];
    const int*   ei     = (const int*)d_in[1];
    const float* pseudo = (const float*)d_in[2];
    const float* weight = (const float*)d_in[3];
    const float* root   = (const float*)d_in[4];
    const float* bias   = (const float*)d_in[5];
    float* out = (float*)d_out;

    // ws layout (int elements)
    int* wsI = (int*)d_ws;
    int* cursor32 = wsI;                        // 32
    int* degi     = wsI + 32;                   // 50000
    int* rcur     = wsI + 50032;                // 50000
    int* rowstart = wsI + 100032;               // 50001 (+15 pad)
    int* bsum     = wsI + 150048;               // 64
    // 150112 ints = 600448 B, 8B-aligned
    unsigned long long* recs = (unsigned long long*)(wsI + 150112);  // 6.91 MB
    unsigned short* msg = (unsigned short*)((char*)d_ws + 600448 + (size_t)NB2 * BCAP * 8);
    const size_t needed = 600448 + (size_t)NB2 * BCAP * 8
                        + (size_t)MSGCAP * COUT * 2;  // ~71.5 MB

    const int eblocks = (E_EDGES + 255) / 256;   // 3125

    if (ws_size >= needed) {
        hipMemsetAsync(d_ws, 0, (size_t)100032 * 4, stream);  // cursor+degi+rcur
        build_recs <<<eblocks, 256, 0, stream>>>(ei, pseudo, cursor32, recs, degi);
        scan_blocks<<<NSCANBLK, 1024, 0, stream>>>(degi, rowstart, bsum);
        scan_finish<<<NSCANBLK, 1024, 0, stream>>>(rowstart, bsum);
        for (int h = 0; h < 2; ++h) {
            bucket_mfma_rec<<<16 * 64, 256, 0, stream>>>(
                x, weight, recs, cursor32, rowstart, rcur, msg, h);
            gather_sum<<<2048, 256, 0, stream>>>(
                msg, rowstart, x, root, bias, out, h * HALF_N);
        }
    } else {
        // R4 fallback layout
        char* w = (char*)d_ws;
        float* degF   = (float*)w;
        int*   histF  = (int*)(w + 200064);
        int*   bstF   = (int*)(w + 200128);
        int*   curF   = (int*)(w + 200192);
        int*   listF  = (int*)(w + 200256);

        hipMemsetAsync(out, 0, sizeof(float) * (size_t)N_NODES * COUT, stream);
        hipMemsetAsync(degF, 0, sizeof(float) * (size_t)N_NODES, stream);
        hipMemsetAsync(histF, 0, 192, stream);

        count_fb      <<<eblocks, 256, 0, stream>>>(ei, pseudo, histF, degF);
        scan16_fb     <<<1, 64, 0, stream>>>(histF, bstF, curF);
        scatter_fb    <<<eblocks, 256, 0, stream>>>(pseudo, curF, listF);
        bucket_mfma_fb<<<16 * 64, 256, 0, stream>>>(x, ei, pseudo, weight, listF,
                                                    bstF, histF, out);
        final_fb      <<<1024, 256, 0, stream>>>(x, root, bias, degF, out);
    }
}

// Round 10
// 249.061 us; speedup vs baseline: 1.4990x; 1.0106x over previous
//
#include <hip/hip_runtime.h>

#define N_NODES 50000
#define HALF_N  25000
#define E_EDGES 800000
#define CIN     32
#define COUT    64
#define NB2     32       // (half, cell) buckets
#define BCAP    27008    // per-bucket record capacity (avg 25000, +10 sigma)
#define NSHARD  4        // degree-counter shards
#define KPAD    136      // 128 bf16 + 8 pad
#define SCANB   1024
#define NSCANBLK ((N_NODES + SCANB - 1) / SCANB)   // 49
#define MSGCAP  500000   // per-half msg slots (actual ~400K)

typedef __attribute__((ext_vector_type(8))) short s8v;   // 8 bf16 = 4 VGPRs
typedef __attribute__((ext_vector_type(4))) float f4v;

static __device__ inline unsigned short f2bf(float f) {  // RTNE fp32->bf16
    unsigned u = __builtin_bit_cast(unsigned, f);
    u += 0x7fff + ((u >> 16) & 1);
    return (unsigned short)(u >> 16);
}
static __device__ inline float bf2f(unsigned short h) {
    unsigned u = ((unsigned)h) << 16;
    return __builtin_bit_cast(float, u);
}

// ================= main (record/CSR) path =================

// fused pass: build (half,cell)-bucketed 8B records + sharded degree count.
// rec = row:16 | col:16 | f0q:16 | f1q:16. degi sharded x4 by blockIdx to cut
// same-line atomic serialization at L2 (contention-theory experiment).
__global__ __launch_bounds__(256) void build_recs(
    const int* __restrict__ ei, const float* __restrict__ pseudo,
    int* __restrict__ cursor, unsigned long long* __restrict__ recs,
    int* __restrict__ degi4)
{
    __shared__ int lh[NB2];
    __shared__ int lbase[NB2];
    if (threadIdx.x < NB2) lh[threadIdx.x] = 0;
    __syncthreads();
    const int e = blockIdx.x * 256 + threadIdx.x;
    int* __restrict__ dshard = degi4 + (size_t)(blockIdx.x & (NSHARD - 1)) * N_NODES;
    int b = 0, myoff = 0;
    unsigned long long rec = 0;
    if (e < E_EDGES) {
        const int row = min(max(ei[e], 0), N_NODES - 1);
        const int col = min(max(ei[E_EDGES + e], 0), N_NODES - 1);
        const float v0 = pseudo[2 * e] * 4.0f, v1 = pseudo[2 * e + 1] * 4.0f;
        const float fl0 = floorf(v0), fl1 = floorf(v1);
        const int lo0 = min(max((int)fl0, 0), 3);
        const int lo1 = min(max((int)fl1, 0), 3);
        const int f0q = min((int)((v0 - fl0) * 65536.0f), 65535);
        const int f1q = min((int)((v1 - fl1) * 65536.0f), 65535);
        const int half = (row >= HALF_N) ? 1 : 0;
        b = half * 16 + lo0 + 4 * lo1;
        rec = (unsigned long long)row
            | ((unsigned long long)col << 16)
            | ((unsigned long long)f0q << 32)
            | ((unsigned long long)f1q << 48);
        myoff = atomicAdd(&lh[b], 1);
        atomicAdd(&dshard[row], 1);          // fire-and-forget, sharded
    }
    __syncthreads();
    if (threadIdx.x < NB2)
        lbase[threadIdx.x] = atomicAdd(&cursor[threadIdx.x], lh[threadIdx.x]);
    __syncthreads();
    if (e < E_EDGES) {
        const int idx = min(lbase[b] + myoff, BCAP - 1);   // defensive clamp
        recs[(size_t)b * BCAP + idx] = rec;
    }
}

// pass B1: per-block local exclusive scan of sum-of-shards
__global__ __launch_bounds__(1024) void scan_blocks(
    const int* __restrict__ degi4, int* __restrict__ rowstart, int* __restrict__ bsum)
{
    __shared__ int wsum[16];
    __shared__ int woff[16];
    const int tid = threadIdx.x, lane = tid & 63, wid = tid >> 6;
    const int n = blockIdx.x * SCANB + tid;
    int v = 0;
    if (n < N_NODES) {
#pragma unroll
        for (int s = 0; s < NSHARD; ++s)
            v += degi4[(size_t)s * N_NODES + n];
    }
    int val = v;
#pragma unroll
    for (int off = 1; off < 64; off <<= 1) {
        int t = __shfl_up(val, off);
        if (lane >= off) val += t;
    }
    if (lane == 63) wsum[wid] = val;
    __syncthreads();
    if (tid == 0) {
        int a = 0;
#pragma unroll
        for (int w = 0; w < 16; ++w) { woff[w] = a; a += wsum[w]; }
        bsum[blockIdx.x] = a;
    }
    __syncthreads();
    if (n < N_NODES) rowstart[n] = woff[wid] + (val - v);
}

// pass B2: each block self-computes its bsum prefix and adds it
__global__ __launch_bounds__(1024) void scan_finish(
    int* __restrict__ rowstart, const int* __restrict__ bsum)
{
    const int b = blockIdx.x;
    int off = 0;
    for (int i = 0; i < NSCANBLK; ++i)          // 49 scalar loads, broadcast
        off += (i < b) ? bsum[i] : 0;
    const int n = b * SCANB + threadIdx.x;
    if (n < N_NODES) rowstart[n] += off;
    if (b == NSCANBLK - 1 && threadIdx.x == 0)
        rowstart[N_NODES] = off + bsum[NSCANBLK - 1];
}

// pass D: per-(half,cell) MFMA; metadata from sequential records;
// basis pre-scaled by 1/deg; msg written to row-sorted slot (per-half buffer)
__global__ __launch_bounds__(256, 2) void bucket_mfma_rec(
    const float* __restrict__ x, const float* __restrict__ weight,
    const unsigned long long* __restrict__ recs,
    const int* __restrict__ cursor,
    const int* __restrict__ rowstart, int* __restrict__ rcur,
    unsigned short* __restrict__ msg, int h)
{
    __shared__ short XS[4][16 * KPAD];

    const int lane = threadIdx.x & 63;
    const int wid  = threadIdx.x >> 6;
    const int cell = blockIdx.x & 15;
    const int beta = h * 16 + cell;
    const int wGlob   = (blockIdx.x >> 4) * 4 + wid;
    const int wStride = (gridDim.x >> 4) * 4;

    const int lo0 = cell & 3, lo1 = cell >> 2;
    const int base = lo0 + 5 * lo1;
    const int offs[4] = {0, 1, 5, 6};
    const int q = lane >> 4;
    const int c = lane & 15;
    const int hbase = rowstart[h * HALF_N];   // uniform

    // B-fragments: Wstack[k=s*32+q*8+j][o=nt*16+c]
    s8v bfr[4][4];
#pragma unroll
    for (int s = 0; s < 4; ++s) {
        const float* wp = weight + (size_t)(base + offs[s]) * (CIN * COUT);
#pragma unroll
        for (int nt = 0; nt < 4; ++nt) {
            union { unsigned short u[8]; s8v v; } tmp;
#pragma unroll
            for (int j = 0; j < 8; ++j)
                tmp.u[j] = f2bf(wp[(q * 8 + j) * COUT + nt * 16 + c]);
            bfr[s][nt] = tmp.v;
        }
    }

    const unsigned long long* brec = recs + (size_t)beta * BCAP;
    const int cnt    = min(cursor[beta], BCAP);
    const int ntiles = (cnt + 15) >> 4;

    for (int t = wGlob; t < ntiles; t += wStride) {
        const int ebase = t * 16;

        int colv = 0, slotv = 0;
        float b0 = 0.f, b1 = 0.f, b2 = 0.f, b3 = 0.f;
        if (lane < 16 && (ebase + lane) < cnt) {
            const unsigned long long rec = brec[ebase + lane];   // sequential
            const int row = (int)(rec & 0xFFFF);
            colv = (int)((rec >> 16) & 0xFFFF);
            const float f0 = (float)(int)((rec >> 32) & 0xFFFF) * (1.0f / 65536.0f);
            const float f1 = (float)(int)((rec >> 48) & 0xFFFF) * (1.0f / 65536.0f);
            const int rs = rowstart[row], re = rowstart[row + 1];   // L2-resident
            const float invd = 1.0f / (float)max(re - rs, 1);
            b0 = (1.0f - f0) * (1.0f - f1) * invd;
            b1 = f0 * (1.0f - f1) * invd;
            b2 = (1.0f - f0) * f1 * invd;
            b3 = f0 * f1 * invd;
            slotv = rs - hbase + atomicAdd(&rcur[row], 1);
        }

        // gather + scale + stage X' (16 x 128 bf16)
        {
            const int eg = lane >> 2, part = lane & 3;
            const int  gc = __shfl(colv, eg);
            const float ss0 = __shfl(b0, eg), ss1 = __shfl(b1, eg);
            const float ss2 = __shfl(b2, eg), ss3 = __shfl(b3, eg);
            const float ss[4] = {ss0, ss1, ss2, ss3};
            const float* xp = x + (size_t)gc * CIN + part * 8;
            float xv[8];
            *(f4v*)&xv[0] = *(const f4v*)xp;
            *(f4v*)&xv[4] = *(const f4v*)(xp + 4);
            short* dst = &XS[wid][eg * KPAD + part * 8];
#pragma unroll
            for (int s = 0; s < 4; ++s) {
                union { unsigned short u[8]; s8v v; } tmp;
#pragma unroll
                for (int j = 0; j < 8; ++j)
                    tmp.u[j] = f2bf(ss[s] * xv[j]);
                *(s8v*)(dst + s * 32) = tmp.v;
            }
        }
        __builtin_amdgcn_wave_barrier();

        s8v afr[4];
        {
            const short* ap = &XS[wid][c * KPAD + q * 8];
#pragma unroll
            for (int ks = 0; ks < 4; ++ks)
                afr[ks] = *(const s8v*)(ap + ks * 32);
        }
        __builtin_amdgcn_wave_barrier();

        f4v acc[4];
#pragma unroll
        for (int nt = 0; nt < 4; ++nt) {
            acc[nt] = (f4v){0.f, 0.f, 0.f, 0.f};
#pragma unroll
            for (int ks = 0; ks < 4; ++ks)
                acc[nt] = __builtin_amdgcn_mfma_f32_16x16x32_bf16(
                    afr[ks], bfr[ks][nt], acc[nt], 0, 0, 0);
        }

        // epilogue: acc -> bf16 tile in LDS, coalesced 128B store per edge
#pragma unroll
        for (int r = 0; r < 4; ++r) {
            const int m = q * 4 + r;
#pragma unroll
            for (int nt = 0; nt < 4; ++nt)
                XS[wid][m * 64 + nt * 16 + c] = (short)f2bf(acc[nt][r]);
        }
        __builtin_amdgcn_wave_barrier();
        {
            const int m2 = lane >> 2;
            int slot2 = __shfl(slotv, m2);
            const bool valid2 = (ebase + m2) < cnt;
            slot2 = min(slot2, MSGCAP - 1);   // defensive
            const short* sp = &XS[wid][lane * 16];
            s8v vlo = *(const s8v*)sp;
            s8v vhi = *(const s8v*)(sp + 8);
            if (valid2) {
                unsigned short* dst = msg + (size_t)slot2 * COUT + (lane & 3) * 16;
                *(s8v*)dst = vlo;
                *(s8v*)(dst + 8) = vhi;
            }
        }
        __builtin_amdgcn_wave_barrier();
    }
}

// pass E: per-node segment sum (msg pre-scaled by 1/deg) + root/bias fuse
__global__ __launch_bounds__(256) void gather_sum(
    const unsigned short* __restrict__ msg, const int* __restrict__ rowstart,
    const float* __restrict__ x, const float* __restrict__ root,
    const float* __restrict__ bias, float* __restrict__ out, int nstart)
{
    const int wave   = (blockIdx.x * blockDim.x + threadIdx.x) >> 6;
    const int lane   = threadIdx.x & 63;
    const int nwaves = (gridDim.x * blockDim.x) >> 6;
    const int hbase  = rowstart[nstart];

    for (int nn = wave; nn < HALF_N; nn += nwaves) {
        const int n  = nstart + nn;
        const int s  = rowstart[n] - hbase;
        const int e2 = rowstart[n + 1] - hbase;
        float acc = 0.f;
#pragma unroll 8
        for (int p = s; p < e2; ++p)
            acc += bf2f(msg[(size_t)p * COUT + lane]);
        const float* xp = x + (size_t)n * CIN;
        float rt = bias[lane];
#pragma unroll
        for (int i = 0; i < CIN; ++i)
            rt += xp[i] * root[i * COUT + lane];
        out[(size_t)n * COUT + lane] = acc + rt;
    }
}

// ================= fallback (R4 atomic) path =================

__global__ __launch_bounds__(256) void count_fb(
    const int* __restrict__ ei, const float* __restrict__ pseudo,
    int* __restrict__ hist, float* __restrict__ deg)
{
    __shared__ int lh[16];
    if (threadIdx.x < 16) lh[threadIdx.x] = 0;
    __syncthreads();
    const int e = blockIdx.x * 256 + threadIdx.x;
    if (e < E_EDGES) {
        int row = min(max(ei[e], 0), N_NODES - 1);
        const float v0 = pseudo[2 * e] * 4.0f, v1 = pseudo[2 * e + 1] * 4.0f;
        const int lo0 = min(max((int)floorf(v0), 0), 3);
        const int lo1 = min(max((int)floorf(v1), 0), 3);
        atomicAdd(&lh[lo0 + 4 * lo1], 1);
        atomicAdd(&deg[row], 1.0f);
    }
    __syncthreads();
    if (threadIdx.x < 16) atomicAdd(&hist[threadIdx.x], lh[threadIdx.x]);
}

__global__ void scan16_fb(const int* __restrict__ hist,
                          int* __restrict__ bstart, int* __restrict__ cursor)
{
    if (threadIdx.x == 0 && blockIdx.x == 0) {
        int acc = 0;
        for (int c = 0; c < 16; ++c) { bstart[c] = acc; cursor[c] = acc; acc += hist[c]; }
    }
}

__global__ __launch_bounds__(256) void scatter_fb(
    const float* __restrict__ pseudo, int* __restrict__ cursor, int* __restrict__ list)
{
    __shared__ int lh[16];
    __shared__ int lbase[16];
    if (threadIdx.x < 16) lh[threadIdx.x] = 0;
    __syncthreads();
    const int e = blockIdx.x * 256 + threadIdx.x;
    int cell = 0, myoff = 0;
    if (e < E_EDGES) {
        const float v0 = pseudo[2 * e] * 4.0f, v1 = pseudo[2 * e + 1] * 4.0f;
        const int lo0 = min(max((int)floorf(v0), 0), 3);
        const int lo1 = min(max((int)floorf(v1), 0), 3);
        cell = lo0 + 4 * lo1;
        myoff = atomicAdd(&lh[cell], 1);
    }
    __syncthreads();
    if (threadIdx.x < 16)
        lbase[threadIdx.x] = atomicAdd(&cursor[threadIdx.x], lh[threadIdx.x]);
    __syncthreads();
    if (e < E_EDGES)
        list[lbase[cell] + myoff] = e;
}

__global__ __launch_bounds__(256, 2) void bucket_mfma_fb(
    const float* __restrict__ x, const int* __restrict__ ei,
    const float* __restrict__ pseudo, const float* __restrict__ weight,
    const int* __restrict__ list, const int* __restrict__ bstart,
    const int* __restrict__ hist, float* __restrict__ out)
{
    __shared__ short XS[4][16 * KPAD];
    const int lane = threadIdx.x & 63;
    const int wid  = threadIdx.x >> 6;
    const int beta = blockIdx.x & 15;
    const int wGlob   = (blockIdx.x >> 4) * 4 + wid;
    const int wStride = (gridDim.x >> 4) * 4;
    const int lo0 = beta & 3, lo1 = beta >> 2;
    const int base = lo0 + 5 * lo1;
    const int offs[4] = {0, 1, 5, 6};
    const int q = lane >> 4, c = lane & 15;

    s8v bfr[4][4];
#pragma unroll
    for (int s = 0; s < 4; ++s) {
        const float* wp = weight + (size_t)(base + offs[s]) * (CIN * COUT);
#pragma unroll
        for (int nt = 0; nt < 4; ++nt) {
            union { unsigned short u[8]; s8v v; } tmp;
#pragma unroll
            for (int j = 0; j < 8; ++j)
                tmp.u[j] = f2bf(wp[(q * 8 + j) * COUT + nt * 16 + c]);
            bfr[s][nt] = tmp.v;
        }
    }
    const int start = bstart[beta], cnt = hist[beta];
    const int ntiles = (cnt + 15) >> 4;

    for (int t = wGlob; t < ntiles; t += wStride) {
        const int ebase = start + t * 16;
        int rowv = 0, colv = 0;
        float b0 = 0.f, b1 = 0.f, b2 = 0.f, b3 = 0.f;
        if (lane < 16 && (t * 16 + lane) < cnt) {
            const int e = list[ebase + lane];
            rowv = min(max(ei[e], 0), N_NODES - 1);
            colv = min(max(ei[E_EDGES + e], 0), N_NODES - 1);
            const float v0 = pseudo[2 * e] * 4.0f, v1 = pseudo[2 * e + 1] * 4.0f;
            const float f0 = v0 - floorf(v0), f1 = v1 - floorf(v1);
            b0 = (1.0f - f0) * (1.0f - f1);
            b1 = f0 * (1.0f - f1);
            b2 = (1.0f - f0) * f1;
            b3 = f0 * f1;
        }
        {
            const int eg = lane >> 2, part = lane & 3;
            const int  gc = __shfl(colv, eg);
            const float ss0 = __shfl(b0, eg), ss1 = __shfl(b1, eg);
            const float ss2 = __shfl(b2, eg), ss3 = __shfl(b3, eg);
            const float ss[4] = {ss0, ss1, ss2, ss3};
            const float* xp = x + (size_t)gc * CIN + part * 8;
            float xv[8];
            *(f4v*)&xv[0] = *(const f4v*)xp;
            *(f4v*)&xv[4] = *(const f4v*)(xp + 4);
            short* dst = &XS[wid][eg * KPAD + part * 8];
#pragma unroll
            for (int s = 0; s < 4; ++s) {
                union { unsigned short u[8]; s8v v; } tmp;
#pragma unroll
                for (int j = 0; j < 8; ++j)
                    tmp.u[j] = f2bf(ss[s] * xv[j]);
                *(s8v*)(dst + s * 32) = tmp.v;
            }
        }
        __builtin_amdgcn_wave_barrier();
        s8v afr[4];
        {
            const short* ap = &XS[wid][c * KPAD + q * 8];
#pragma unroll
            for (int ks = 0; ks < 4; ++ks)
                afr[ks] = *(const s8v*)(ap + ks * 32);
        }
        __builtin_amdgcn_wave_barrier();
        f4v acc[4];
#pragma unroll
        for (int nt = 0; nt < 4; ++nt) {
            acc[nt] = (f4v){0.f, 0.f, 0.f, 0.f};
#pragma unroll
            for (int ks = 0; ks < 4; ++ks)
                acc[nt] = __builtin_amdgcn_mfma_f32_16x16x32_bf16(
                    afr[ks], bfr[ks][nt], acc[nt], 0, 0, 0);
        }
#pragma unroll
        for (int r = 0; r < 4; ++r) {
            const int m = q * 4 + r;
            const int orow = __shfl(rowv, m);
#pragma unroll
            for (int nt = 0; nt < 4; ++nt)
                atomicAdd(&out[(size_t)orow * COUT + nt * 16 + c], acc[nt][r]);
        }
    }
}

__global__ __launch_bounds__(256) void final_fb(
    const float* __restrict__ x, const float* __restrict__ root,
    const float* __restrict__ bias, const float* __restrict__ deg,
    float* __restrict__ out)
{
    const int wave   = (blockIdx.x * blockDim.x + threadIdx.x) >> 6;
    const int lane   = threadIdx.x & 63;
    const int nwaves = (gridDim.x * blockDim.x) >> 6;
    for (int n = wave; n < N_NODES; n += nwaves) {
        const float* xp = x + (size_t)n * CIN;
        float acc = bias[lane];
#pragma unroll
        for (int i = 0; i < CIN; ++i)
            acc += xp[i] * root[i * COUT + lane];
        float dg = deg[n];
        dg = dg > 1.0f ? dg : 1.0f;
        const size_t idx = (size_t)n * COUT + lane;
        out[idx] = out[idx] / dg + acc;
    }
}

extern "C" void kernel_launch(void* const* d_in, const int* in_sizes, int n_in,
                              void* d_out, int out_size, void* d_ws, size_t ws_size,
                              hipStream_t stream) {
    const float* x      = (const float*)d_in[0];
    const int*   ei     = (const int*)d_in[1];
    const float* pseudo = (const float*)d_in[2];
    const float* weight = (const float*)d_in[3];
    const float* root   = (const float*)d_in[4];
    const float* bias   = (const float*)d_in[5];
    float* out = (float*)d_out;

    // ws layout (int elements)
    int* wsI = (int*)d_ws;
    int* cursor32 = wsI;                         // 32
    int* degi4    = wsI + 32;                    // 4 x 50000
    int* rcur     = wsI + 200032;                // 50000
    int* rowstart = wsI + 250032;                // 50001 (+15 pad)
    int* bsum     = wsI + 300048;                // 64
    // 300112 ints = 1200448 B, 8B-aligned
    unsigned long long* recs = (unsigned long long*)(wsI + 300112);  // 6.91 MB
    unsigned short* msg = (unsigned short*)((char*)d_ws + 1200448 + (size_t)NB2 * BCAP * 8);
    const size_t needed = 1200448 + (size_t)NB2 * BCAP * 8
                        + (size_t)MSGCAP * COUT * 2;  // ~72.1 MB

    const int eblocks = (E_EDGES + 255) / 256;   // 3125

    if (ws_size >= needed) {
        hipMemsetAsync(d_ws, 0, (size_t)250032 * 4, stream);  // cursor+degi4+rcur
        build_recs <<<eblocks, 256, 0, stream>>>(ei, pseudo, cursor32, recs, degi4);
        scan_blocks<<<NSCANBLK, 1024, 0, stream>>>(degi4, rowstart, bsum);
        scan_finish<<<NSCANBLK, 1024, 0, stream>>>(rowstart, bsum);
        for (int h = 0; h < 2; ++h) {
            bucket_mfma_rec<<<16 * 64, 256, 0, stream>>>(
                x, weight, recs, cursor32, rowstart, rcur, msg, h);
            gather_sum<<<2048, 256, 0, stream>>>(
                msg, rowstart, x, root, bias, out, h * HALF_N);
        }
    } else {
        // R4 fallback layout
        char* w = (char*)d_ws;
        float* degF   = (float*)w;
        int*   histF  = (int*)(w + 200064);
        int*   bstF   = (int*)(w + 200128);
        int*   curF   = (int*)(w + 200192);
        int*   listF  = (int*)(w + 200256);

        hipMemsetAsync(out, 0, sizeof(float) * (size_t)N_NODES * COUT, stream);
        hipMemsetAsync(degF, 0, sizeof(float) * (size_t)N_NODES, stream);
        hipMemsetAsync(histF, 0, 192, stream);

        count_fb      <<<eblocks, 256, 0, stream>>>(ei, pseudo, histF, degF);
        scan16_fb     <<<1, 64, 0, stream>>>(histF, bstF, curF);
        scatter_fb    <<<eblocks, 256, 0, stream>>>(pseudo, curF, listF);
        bucket_mfma_fb<<<16 * 64, 256, 0, stream>>>(x, ei, pseudo, weight, listF,
                                                    bstF, histF, out);
        final_fb      <<<1024, 256, 0, stream>>>(x, root, bias, degF, out);
    }
}

// Round 11
// 223.504 us; speedup vs baseline: 1.6704x; 1.1143x over previous
//
#include <hip/hip_runtime.h>

#define N_NODES 50000
#define HALF_N  25000
#define E_EDGES 800000
#define CIN     32
#define COUT    64
#define NB2     32       // (half, cell) buckets
#define BCAP    27008    // per-bucket record capacity (avg 25000, +10 sigma)
#define NSHARD  4        // degree-counter shards
#define KPAD    136      // 128 bf16 + 8 pad
#define SCANB   1024
#define NSCANBLK ((N_NODES + SCANB - 1) / SCANB)   // 49
#define MSGCAP  500000   // per-half msg slots (actual ~400K)
#define EPB     8        // edges per thread in build_recs
#define BBLK    ((E_EDGES + EPB * 256 - 1) / (EPB * 256))   // 391 blocks

typedef __attribute__((ext_vector_type(8))) short s8v;   // 8 bf16 = 4 VGPRs
typedef __attribute__((ext_vector_type(4))) float f4v;

static __device__ inline unsigned short f2bf(float f) {  // RTNE fp32->bf16
    unsigned u = __builtin_bit_cast(unsigned, f);
    u += 0x7fff + ((u >> 16) & 1);
    return (unsigned short)(u >> 16);
}
static __device__ inline float bf2f(unsigned short h) {
    unsigned u = ((unsigned)h) << 16;
    return __builtin_bit_cast(float, u);
}

// ================= main (record/CSR) path =================

// fused pass: build (half,cell)-bucketed 8B records + sharded degree count.
// rec = row:16 | col:16 | f0q:16 | f1q:16.
// 391 blocks x 8 edges/thread: records cached in registers (sweep 1), ONE
// cursor atomic per bucket per block (391 serial RMW/address vs 3125 before
// -- theory (c): that per-address depth was the 63us wall), then sweep-2
// register->recs writes.
__global__ __launch_bounds__(256) void build_recs(
    const int* __restrict__ ei, const float* __restrict__ pseudo,
    int* __restrict__ cursor, unsigned long long* __restrict__ recs,
    int* __restrict__ degi4)
{
    __shared__ int lh[NB2];
    __shared__ int lbase[NB2];
    if (threadIdx.x < NB2) lh[threadIdx.x] = 0;
    __syncthreads();

    int* __restrict__ dshard = degi4 + (size_t)(blockIdx.x & (NSHARD - 1)) * N_NODES;
    const int ebase0 = blockIdx.x * (EPB * 256);

    unsigned long long rcache[EPB];
    int pcache[EPB];   // b | myoff<<8  (myoff < 2048)

    // sweep 1: compute, LDS-count (myoff = unique in-block offset), cache
#pragma unroll
    for (int i = 0; i < EPB; ++i) {
        const int e = ebase0 + i * 256 + threadIdx.x;
        pcache[i] = -1;
        if (e < E_EDGES) {
            const int row = min(max(ei[e], 0), N_NODES - 1);
            const int col = min(max(ei[E_EDGES + e], 0), N_NODES - 1);
            const float v0 = pseudo[2 * e] * 4.0f, v1 = pseudo[2 * e + 1] * 4.0f;
            const float fl0 = floorf(v0), fl1 = floorf(v1);
            const int lo0 = min(max((int)fl0, 0), 3);
            const int lo1 = min(max((int)fl1, 0), 3);
            const int f0q = min((int)((v0 - fl0) * 65536.0f), 65535);
            const int f1q = min((int)((v1 - fl1) * 65536.0f), 65535);
            const int half = (row >= HALF_N) ? 1 : 0;
            const int b = half * 16 + lo0 + 4 * lo1;
            rcache[i] = (unsigned long long)row
                      | ((unsigned long long)col << 16)
                      | ((unsigned long long)f0q << 32)
                      | ((unsigned long long)f1q << 48);
            const int myoff = atomicAdd(&lh[b], 1);
            pcache[i] = b | (myoff << 8);
            atomicAdd(&dshard[row], 1);     // scattered: ~16 RMW/addr, cheap
        }
    }
    __syncthreads();

    // one global cursor RMW per bucket per block
    if (threadIdx.x < NB2)
        lbase[threadIdx.x] = atomicAdd(&cursor[threadIdx.x], lh[threadIdx.x]);
    __syncthreads();

    // sweep 2: write cached records to claimed slots
#pragma unroll
    for (int i = 0; i < EPB; ++i) {
        if (pcache[i] >= 0) {
            const int b = pcache[i] & 0xFF;
            const int myoff = pcache[i] >> 8;
            const int idx = min(lbase[b] + myoff, BCAP - 1);   // defensive
            recs[(size_t)b * BCAP + idx] = rcache[i];
        }
    }
}

// pass B1: per-block local exclusive scan of sum-of-shards
__global__ __launch_bounds__(1024) void scan_blocks(
    const int* __restrict__ degi4, int* __restrict__ rowstart, int* __restrict__ bsum)
{
    __shared__ int wsum[16];
    __shared__ int woff[16];
    const int tid = threadIdx.x, lane = tid & 63, wid = tid >> 6;
    const int n = blockIdx.x * SCANB + tid;
    int v = 0;
    if (n < N_NODES) {
#pragma unroll
        for (int s = 0; s < NSHARD; ++s)
            v += degi4[(size_t)s * N_NODES + n];
    }
    int val = v;
#pragma unroll
    for (int off = 1; off < 64; off <<= 1) {
        int t = __shfl_up(val, off);
        if (lane >= off) val += t;
    }
    if (lane == 63) wsum[wid] = val;
    __syncthreads();
    if (tid == 0) {
        int a = 0;
#pragma unroll
        for (int w = 0; w < 16; ++w) { woff[w] = a; a += wsum[w]; }
        bsum[blockIdx.x] = a;
    }
    __syncthreads();
    if (n < N_NODES) rowstart[n] = woff[wid] + (val - v);
}

// pass B2: each block self-computes its bsum prefix and adds it
__global__ __launch_bounds__(1024) void scan_finish(
    int* __restrict__ rowstart, const int* __restrict__ bsum)
{
    const int b = blockIdx.x;
    int off = 0;
    for (int i = 0; i < NSCANBLK; ++i)          // 49 scalar loads, broadcast
        off += (i < b) ? bsum[i] : 0;
    const int n = b * SCANB + threadIdx.x;
    if (n < N_NODES) rowstart[n] += off;
    if (b == NSCANBLK - 1 && threadIdx.x == 0)
        rowstart[N_NODES] = off + bsum[NSCANBLK - 1];
}

// pass D: per-(half,cell) MFMA; metadata from sequential records;
// basis pre-scaled by 1/deg; msg written to row-sorted slot (per-half buffer)
__global__ __launch_bounds__(256, 2) void bucket_mfma_rec(
    const float* __restrict__ x, const float* __restrict__ weight,
    const unsigned long long* __restrict__ recs,
    const int* __restrict__ cursor,
    const int* __restrict__ rowstart, int* __restrict__ rcur,
    unsigned short* __restrict__ msg, int h)
{
    __shared__ short XS[4][16 * KPAD];

    const int lane = threadIdx.x & 63;
    const int wid  = threadIdx.x >> 6;
    const int cell = blockIdx.x & 15;
    const int beta = h * 16 + cell;
    const int wGlob   = (blockIdx.x >> 4) * 4 + wid;
    const int wStride = (gridDim.x >> 4) * 4;

    const int lo0 = cell & 3, lo1 = cell >> 2;
    const int base = lo0 + 5 * lo1;
    const int offs[4] = {0, 1, 5, 6};
    const int q = lane >> 4;
    const int c = lane & 15;
    const int hbase = rowstart[h * HALF_N];   // uniform

    // B-fragments: Wstack[k=s*32+q*8+j][o=nt*16+c]
    s8v bfr[4][4];
#pragma unroll
    for (int s = 0; s < 4; ++s) {
        const float* wp = weight + (size_t)(base + offs[s]) * (CIN * COUT);
#pragma unroll
        for (int nt = 0; nt < 4; ++nt) {
            union { unsigned short u[8]; s8v v; } tmp;
#pragma unroll
            for (int j = 0; j < 8; ++j)
                tmp.u[j] = f2bf(wp[(q * 8 + j) * COUT + nt * 16 + c]);
            bfr[s][nt] = tmp.v;
        }
    }

    const unsigned long long* brec = recs + (size_t)beta * BCAP;
    const int cnt    = min(cursor[beta], BCAP);
    const int ntiles = (cnt + 15) >> 4;

    for (int t = wGlob; t < ntiles; t += wStride) {
        const int ebase = t * 16;

        int colv = 0, slotv = 0;
        float b0 = 0.f, b1 = 0.f, b2 = 0.f, b3 = 0.f;
        if (lane < 16 && (ebase + lane) < cnt) {
            const unsigned long long rec = brec[ebase + lane];   // sequential
            const int row = (int)(rec & 0xFFFF);
            colv = (int)((rec >> 16) & 0xFFFF);
            const float f0 = (float)(int)((rec >> 32) & 0xFFFF) * (1.0f / 65536.0f);
            const float f1 = (float)(int)((rec >> 48) & 0xFFFF) * (1.0f / 65536.0f);
            const int rs = rowstart[row], re = rowstart[row + 1];   // L2-resident
            const float invd = 1.0f / (float)max(re - rs, 1);
            b0 = (1.0f - f0) * (1.0f - f1) * invd;
            b1 = f0 * (1.0f - f1) * invd;
            b2 = (1.0f - f0) * f1 * invd;
            b3 = f0 * f1 * invd;
            slotv = rs - hbase + atomicAdd(&rcur[row], 1);   // ~16 RMW/addr
        }

        // gather + scale + stage X' (16 x 128 bf16)
        {
            const int eg = lane >> 2, part = lane & 3;
            const int  gc = __shfl(colv, eg);
            const float ss0 = __shfl(b0, eg), ss1 = __shfl(b1, eg);
            const float ss2 = __shfl(b2, eg), ss3 = __shfl(b3, eg);
            const float ss[4] = {ss0, ss1, ss2, ss3};
            const float* xp = x + (size_t)gc * CIN + part * 8;
            float xv[8];
            *(f4v*)&xv[0] = *(const f4v*)xp;
            *(f4v*)&xv[4] = *(const f4v*)(xp + 4);
            short* dst = &XS[wid][eg * KPAD + part * 8];
#pragma unroll
            for (int s = 0; s < 4; ++s) {
                union { unsigned short u[8]; s8v v; } tmp;
#pragma unroll
                for (int j = 0; j < 8; ++j)
                    tmp.u[j] = f2bf(ss[s] * xv[j]);
                *(s8v*)(dst + s * 32) = tmp.v;
            }
        }
        __builtin_amdgcn_wave_barrier();

        s8v afr[4];
        {
            const short* ap = &XS[wid][c * KPAD + q * 8];
#pragma unroll
            for (int ks = 0; ks < 4; ++ks)
                afr[ks] = *(const s8v*)(ap + ks * 32);
        }
        __builtin_amdgcn_wave_barrier();

        f4v acc[4];
#pragma unroll
        for (int nt = 0; nt < 4; ++nt) {
            acc[nt] = (f4v){0.f, 0.f, 0.f, 0.f};
#pragma unroll
            for (int ks = 0; ks < 4; ++ks)
                acc[nt] = __builtin_amdgcn_mfma_f32_16x16x32_bf16(
                    afr[ks], bfr[ks][nt], acc[nt], 0, 0, 0);
        }

        // epilogue: acc -> bf16 tile in LDS, coalesced 128B store per edge
#pragma unroll
        for (int r = 0; r < 4; ++r) {
            const int m = q * 4 + r;
#pragma unroll
            for (int nt = 0; nt < 4; ++nt)
                XS[wid][m * 64 + nt * 16 + c] = (short)f2bf(acc[nt][r]);
        }
        __builtin_amdgcn_wave_barrier();
        {
            const int m2 = lane >> 2;
            int slot2 = __shfl(slotv, m2);
            const bool valid2 = (ebase + m2) < cnt;
            slot2 = min(slot2, MSGCAP - 1);   // defensive
            const short* sp = &XS[wid][lane * 16];
            s8v vlo = *(const s8v*)sp;
            s8v vhi = *(const s8v*)(sp + 8);
            if (valid2) {
                unsigned short* dst = msg + (size_t)slot2 * COUT + (lane & 3) * 16;
                *(s8v*)dst = vlo;
                *(s8v*)(dst + 8) = vhi;
            }
        }
        __builtin_amdgcn_wave_barrier();
    }
}

// pass E: per-node segment sum (msg pre-scaled by 1/deg) + root/bias fuse
__global__ __launch_bounds__(256) void gather_sum(
    const unsigned short* __restrict__ msg, const int* __restrict__ rowstart,
    const float* __restrict__ x, const float* __restrict__ root,
    const float* __restrict__ bias, float* __restrict__ out, int nstart)
{
    const int wave   = (blockIdx.x * blockDim.x + threadIdx.x) >> 6;
    const int lane   = threadIdx.x & 63;
    const int nwaves = (gridDim.x * blockDim.x) >> 6;
    const int hbase  = rowstart[nstart];

    for (int nn = wave; nn < HALF_N; nn += nwaves) {
        const int n  = nstart + nn;
        const int s  = rowstart[n] - hbase;
        const int e2 = rowstart[n + 1] - hbase;
        float acc = 0.f;
#pragma unroll 8
        for (int p = s; p < e2; ++p)
            acc += bf2f(msg[(size_t)p * COUT + lane]);
        const float* xp = x + (size_t)n * CIN;
        float rt = bias[lane];
#pragma unroll
        for (int i = 0; i < CIN; ++i)
            rt += xp[i] * root[i * COUT + lane];
        out[(size_t)n * COUT + lane] = acc + rt;
    }
}

// ================= fallback (R4 atomic) path =================

__global__ __launch_bounds__(256) void count_fb(
    const int* __restrict__ ei, const float* __restrict__ pseudo,
    int* __restrict__ hist, float* __restrict__ deg)
{
    __shared__ int lh[16];
    if (threadIdx.x < 16) lh[threadIdx.x] = 0;
    __syncthreads();
    const int e = blockIdx.x * 256 + threadIdx.x;
    if (e < E_EDGES) {
        int row = min(max(ei[e], 0), N_NODES - 1);
        const float v0 = pseudo[2 * e] * 4.0f, v1 = pseudo[2 * e + 1] * 4.0f;
        const int lo0 = min(max((int)floorf(v0), 0), 3);
        const int lo1 = min(max((int)floorf(v1), 0), 3);
        atomicAdd(&lh[lo0 + 4 * lo1], 1);
        atomicAdd(&deg[row], 1.0f);
    }
    __syncthreads();
    if (threadIdx.x < 16) atomicAdd(&hist[threadIdx.x], lh[threadIdx.x]);
}

__global__ void scan16_fb(const int* __restrict__ hist,
                          int* __restrict__ bstart, int* __restrict__ cursor)
{
    if (threadIdx.x == 0 && blockIdx.x == 0) {
        int acc = 0;
        for (int c = 0; c < 16; ++c) { bstart[c] = acc; cursor[c] = acc; acc += hist[c]; }
    }
}

__global__ __launch_bounds__(256) void scatter_fb(
    const float* __restrict__ pseudo, int* __restrict__ cursor, int* __restrict__ list)
{
    __shared__ int lh[16];
    __shared__ int lbase[16];
    if (threadIdx.x < 16) lh[threadIdx.x] = 0;
    __syncthreads();
    const int e = blockIdx.x * 256 + threadIdx.x;
    int cell = 0, myoff = 0;
    if (e < E_EDGES) {
        const float v0 = pseudo[2 * e] * 4.0f, v1 = pseudo[2 * e + 1] * 4.0f;
        const int lo0 = min(max((int)floorf(v0), 0), 3);
        const int lo1 = min(max((int)floorf(v1), 0), 3);
        cell = lo0 + 4 * lo1;
        myoff = atomicAdd(&lh[cell], 1);
    }
    __syncthreads();
    if (threadIdx.x < 16)
        lbase[threadIdx.x] = atomicAdd(&cursor[threadIdx.x], lh[threadIdx.x]);
    __syncthreads();
    if (e < E_EDGES)
        list[lbase[cell] + myoff] = e;
}

__global__ __launch_bounds__(256, 2) void bucket_mfma_fb(
    const float* __restrict__ x, const int* __restrict__ ei,
    const float* __restrict__ pseudo, const float* __restrict__ weight,
    const int* __restrict__ list, const int* __restrict__ bstart,
    const int* __restrict__ hist, float* __restrict__ out)
{
    __shared__ short XS[4][16 * KPAD];
    const int lane = threadIdx.x & 63;
    const int wid  = threadIdx.x >> 6;
    const int beta = blockIdx.x & 15;
    const int wGlob   = (blockIdx.x >> 4) * 4 + wid;
    const int wStride = (gridDim.x >> 4) * 4;
    const int lo0 = beta & 3, lo1 = beta >> 2;
    const int base = lo0 + 5 * lo1;
    const int offs[4] = {0, 1, 5, 6};
    const int q = lane >> 4, c = lane & 15;

    s8v bfr[4][4];
#pragma unroll
    for (int s = 0; s < 4; ++s) {
        const float* wp = weight + (size_t)(base + offs[s]) * (CIN * COUT);
#pragma unroll
        for (int nt = 0; nt < 4; ++nt) {
            union { unsigned short u[8]; s8v v; } tmp;
#pragma unroll
            for (int j = 0; j < 8; ++j)
                tmp.u[j] = f2bf(wp[(q * 8 + j) * COUT + nt * 16 + c]);
            bfr[s][nt] = tmp.v;
        }
    }
    const int start = bstart[beta], cnt = hist[beta];
    const int ntiles = (cnt + 15) >> 4;

    for (int t = wGlob; t < ntiles; t += wStride) {
        const int ebase = start + t * 16;
        int rowv = 0, colv = 0;
        float b0 = 0.f, b1 = 0.f, b2 = 0.f, b3 = 0.f;
        if (lane < 16 && (t * 16 + lane) < cnt) {
            const int e = list[ebase + lane];
            rowv = min(max(ei[e], 0), N_NODES - 1);
            colv = min(max(ei[E_EDGES + e], 0), N_NODES - 1);
            const float v0 = pseudo[2 * e] * 4.0f, v1 = pseudo[2 * e + 1] * 4.0f;
            const float f0 = v0 - floorf(v0), f1 = v1 - floorf(v1);
            b0 = (1.0f - f0) * (1.0f - f1);
            b1 = f0 * (1.0f - f1);
            b2 = (1.0f - f0) * f1;
            b3 = f0 * f1;
        }
        {
            const int eg = lane >> 2, part = lane & 3;
            const int  gc = __shfl(colv, eg);
            const float ss0 = __shfl(b0, eg), ss1 = __shfl(b1, eg);
            const float ss2 = __shfl(b2, eg), ss3 = __shfl(b3, eg);
            const float ss[4] = {ss0, ss1, ss2, ss3};
            const float* xp = x + (size_t)gc * CIN + part * 8;
            float xv[8];
            *(f4v*)&xv[0] = *(const f4v*)xp;
            *(f4v*)&xv[4] = *(const f4v*)(xp + 4);
            short* dst = &XS[wid][eg * KPAD + part * 8];
#pragma unroll
            for (int s = 0; s < 4; ++s) {
                union { unsigned short u[8]; s8v v; } tmp;
#pragma unroll
                for (int j = 0; j < 8; ++j)
                    tmp.u[j] = f2bf(ss[s] * xv[j]);
                *(s8v*)(dst + s * 32) = tmp.v;
            }
        }
        __builtin_amdgcn_wave_barrier();
        s8v afr[4];
        {
            const short* ap = &XS[wid][c * KPAD + q * 8];
#pragma unroll
            for (int ks = 0; ks < 4; ++ks)
                afr[ks] = *(const s8v*)(ap + ks * 32);
        }
        __builtin_amdgcn_wave_barrier();
        f4v acc[4];
#pragma unroll
        for (int nt = 0; nt < 4; ++nt) {
            acc[nt] = (f4v){0.f, 0.f, 0.f, 0.f};
#pragma unroll
            for (int ks = 0; ks < 4; ++ks)
                acc[nt] = __builtin_amdgcn_mfma_f32_16x16x32_bf16(
                    afr[ks], bfr[ks][nt], acc[nt], 0, 0, 0);
        }
#pragma unroll
        for (int r = 0; r < 4; ++r) {
            const int m = q * 4 + r;
            const int orow = __shfl(rowv, m);
#pragma unroll
            for (int nt = 0; nt < 4; ++nt)
                atomicAdd(&out[(size_t)orow * COUT + nt * 16 + c], acc[nt][r]);
        }
    }
}

__global__ __launch_bounds__(256) void final_fb(
    const float* __restrict__ x, const float* __restrict__ root,
    const float* __restrict__ bias, const float* __restrict__ deg,
    float* __restrict__ out)
{
    const int wave   = (blockIdx.x * blockDim.x + threadIdx.x) >> 6;
    const int lane   = threadIdx.x & 63;
    const int nwaves = (gridDim.x * blockDim.x) >> 6;
    for (int n = wave; n < N_NODES; n += nwaves) {
        const float* xp = x + (size_t)n * CIN;
        float acc = bias[lane];
#pragma unroll
        for (int i = 0; i < CIN; ++i)
            acc += xp[i] * root[i * COUT + lane];
        float dg = deg[n];
        dg = dg > 1.0f ? dg : 1.0f;
        const size_t idx = (size_t)n * COUT + lane;
        out[idx] = out[idx] / dg + acc;
    }
}

extern "C" void kernel_launch(void* const* d_in, const int* in_sizes, int n_in,
                              void* d_out, int out_size, void* d_ws, size_t ws_size,
                              hipStream_t stream) {
    const float* x      = (const float*)d_in[0];
    const int*   ei     = (const int*)d_in[1];
    const float* pseudo = (const float*)d_in[2];
    const float* weight = (const float*)d_in[3];
    const float* root   = (const float*)d_in[4];
    const float* bias   = (const float*)d_in[5];
    float* out = (float*)d_out;

    // ws layout (int elements)
    int* wsI = (int*)d_ws;
    int* cursor32 = wsI;                         // 32
    int* degi4    = wsI + 32;                    // 4 x 50000
    int* rcur     = wsI + 200032;                // 50000
    int* rowstart = wsI + 250032;                // 50001 (+15 pad)
    int* bsum     = wsI + 300048;                // 64
    // 300112 ints = 1200448 B, 8B-aligned
    unsigned long long* recs = (unsigned long long*)(wsI + 300112);  // 6.91 MB
    unsigned short* msg = (unsigned short*)((char*)d_ws + 1200448 + (size_t)NB2 * BCAP * 8);
    const size_t needed = 1200448 + (size_t)NB2 * BCAP * 8
                        + (size_t)MSGCAP * COUT * 2;  // ~72.1 MB

    if (ws_size >= needed) {
        hipMemsetAsync(d_ws, 0, (size_t)250032 * 4, stream);  // cursor+degi4+rcur
        build_recs <<<BBLK, 256, 0, stream>>>(ei, pseudo, cursor32, recs, degi4);
        scan_blocks<<<NSCANBLK, 1024, 0, stream>>>(degi4, rowstart, bsum);
        scan_finish<<<NSCANBLK, 1024, 0, stream>>>(rowstart, bsum);
        for (int h = 0; h < 2; ++h) {
            bucket_mfma_rec<<<16 * 64, 256, 0, stream>>>(
                x, weight, recs, cursor32, rowstart, rcur, msg, h);
            gather_sum<<<2048, 256, 0, stream>>>(
                msg, rowstart, x, root, bias, out, h * HALF_N);
        }
    } else {
        // R4 fallback layout
        char* w = (char*)d_ws;
        float* degF   = (float*)w;
        int*   histF  = (int*)(w + 200064);
        int*   bstF   = (int*)(w + 200128);
        int*   curF   = (int*)(w + 200192);
        int*   listF  = (int*)(w + 200256);
        const int eblocks = (E_EDGES + 255) / 256;

        hipMemsetAsync(out, 0, sizeof(float) * (size_t)N_NODES * COUT, stream);
        hipMemsetAsync(degF, 0, sizeof(float) * (size_t)N_NODES, stream);
        hipMemsetAsync(histF, 0, 192, stream);

        count_fb      <<<eblocks, 256, 0, stream>>>(ei, pseudo, histF, degF);
        scan16_fb     <<<1, 64, 0, stream>>>(histF, bstF, curF);
        scatter_fb    <<<eblocks, 256, 0, stream>>>(pseudo, curF, listF);
        bucket_mfma_fb<<<16 * 64, 256, 0, stream>>>(x, ei, pseudo, weight, listF,
                                                    bstF, histF, out);
        final_fb      <<<1024, 256, 0, stream>>>(x, root, bias, degF, out);
    }
}

// Round 12
// 203.087 us; speedup vs baseline: 1.8383x; 1.1005x over previous
//
#include <hip/hip_runtime.h>

#define N_NODES 50000
#define E_EDGES 800000
#define CIN     32
#define COUT    64
#define NB      16       // cell buckets
#define BCAP    54016    // per-bucket record capacity (avg 50000, +18 sigma)
#define NSHARD  4        // degree-counter shards
#define KPAD    136      // 128 bf16 + 8 pad
#define SCANB   1024
#define NSCANBLK ((N_NODES + SCANB - 1) / SCANB)   // 49
#define MSGCAP  800016   // full-E msg slots
#define EPB     8        // edges per thread in build_recs
#define BBLK    ((E_EDGES + EPB * 256 - 1) / (EPB * 256))   // 391 blocks

typedef __attribute__((ext_vector_type(8))) short s8v;   // 8 bf16 = 4 VGPRs
typedef __attribute__((ext_vector_type(4))) float f4v;
typedef __attribute__((ext_vector_type(4))) unsigned short u4v;

static __device__ inline unsigned short f2bf(float f) {  // RTNE fp32->bf16
    unsigned u = __builtin_bit_cast(unsigned, f);
    u += 0x7fff + ((u >> 16) & 1);
    return (unsigned short)(u >> 16);
}
static __device__ inline float bf2f(unsigned short h) {
    unsigned u = ((unsigned)h) << 16;
    return __builtin_bit_cast(float, u);
}

// ================= main (record/CSR, single-pass) path =================

// x (fp32) -> xbf (bf16): halves the random gather line traffic in pass D
__global__ __launch_bounds__(256) void x2bf_kernel(
    const float* __restrict__ x, unsigned short* __restrict__ xbf)
{
    const int i = blockIdx.x * 256 + threadIdx.x;
    const int total = N_NODES * CIN / 4;
    if (i < total) {
        f4v v = *(const f4v*)(x + (size_t)i * 4);
        u4v o = { f2bf(v[0]), f2bf(v[1]), f2bf(v[2]), f2bf(v[3]) };
        *(u4v*)(xbf + (size_t)i * 4) = o;
    }
}

// fused pass: build cell-bucketed 8B records + sharded degree count.
// rec = row:16 | col:16 | f0q:16 | f1q:16.
// 391 blocks x 8 edges/thread; ONE cursor atomic per bucket per block
// (391 serial RMW/address -- R11 confirmed this was the 63us wall).
__global__ __launch_bounds__(256) void build_recs(
    const int* __restrict__ ei, const float* __restrict__ pseudo,
    int* __restrict__ cursor, unsigned long long* __restrict__ recs,
    int* __restrict__ degi4)
{
    __shared__ int lh[NB];
    __shared__ int lbase[NB];
    if (threadIdx.x < NB) lh[threadIdx.x] = 0;
    __syncthreads();

    int* __restrict__ dshard = degi4 + (size_t)(blockIdx.x & (NSHARD - 1)) * N_NODES;
    const int ebase0 = blockIdx.x * (EPB * 256);

    unsigned long long rcache[EPB];
    int pcache[EPB];   // b | myoff<<8  (myoff < 2048)

#pragma unroll
    for (int i = 0; i < EPB; ++i) {
        const int e = ebase0 + i * 256 + threadIdx.x;
        pcache[i] = -1;
        if (e < E_EDGES) {
            const int row = min(max(ei[e], 0), N_NODES - 1);
            const int col = min(max(ei[E_EDGES + e], 0), N_NODES - 1);
            const float v0 = pseudo[2 * e] * 4.0f, v1 = pseudo[2 * e + 1] * 4.0f;
            const float fl0 = floorf(v0), fl1 = floorf(v1);
            const int lo0 = min(max((int)fl0, 0), 3);
            const int lo1 = min(max((int)fl1, 0), 3);
            const int f0q = min((int)((v0 - fl0) * 65536.0f), 65535);
            const int f1q = min((int)((v1 - fl1) * 65536.0f), 65535);
            const int b = lo0 + 4 * lo1;
            rcache[i] = (unsigned long long)row
                      | ((unsigned long long)col << 16)
                      | ((unsigned long long)f0q << 32)
                      | ((unsigned long long)f1q << 48);
            const int myoff = atomicAdd(&lh[b], 1);
            pcache[i] = b | (myoff << 8);
            atomicAdd(&dshard[row], 1);     // scattered: ~16 RMW/addr, cheap
        }
    }
    __syncthreads();

    if (threadIdx.x < NB)
        lbase[threadIdx.x] = atomicAdd(&cursor[threadIdx.x], lh[threadIdx.x]);
    __syncthreads();

#pragma unroll
    for (int i = 0; i < EPB; ++i) {
        if (pcache[i] >= 0) {
            const int b = pcache[i] & 0xFF;
            const int myoff = pcache[i] >> 8;
            const int idx = min(lbase[b] + myoff, BCAP - 1);   // defensive
            recs[(size_t)b * BCAP + idx] = rcache[i];
        }
    }
}

// pass B1: per-block local exclusive scan of sum-of-shards
__global__ __launch_bounds__(1024) void scan_blocks(
    const int* __restrict__ degi4, int* __restrict__ rowstart, int* __restrict__ bsum)
{
    __shared__ int wsum[16];
    __shared__ int woff[16];
    const int tid = threadIdx.x, lane = tid & 63, wid = tid >> 6;
    const int n = blockIdx.x * SCANB + tid;
    int v = 0;
    if (n < N_NODES) {
#pragma unroll
        for (int s = 0; s < NSHARD; ++s)
            v += degi4[(size_t)s * N_NODES + n];
    }
    int val = v;
#pragma unroll
    for (int off = 1; off < 64; off <<= 1) {
        int t = __shfl_up(val, off);
        if (lane >= off) val += t;
    }
    if (lane == 63) wsum[wid] = val;
    __syncthreads();
    if (tid == 0) {
        int a = 0;
#pragma unroll
        for (int w = 0; w < 16; ++w) { woff[w] = a; a += wsum[w]; }
        bsum[blockIdx.x] = a;
    }
    __syncthreads();
    if (n < N_NODES) rowstart[n] = woff[wid] + (val - v);
}

// pass B2: each block self-computes its bsum prefix and adds it
__global__ __launch_bounds__(1024) void scan_finish(
    int* __restrict__ rowstart, const int* __restrict__ bsum)
{
    const int b = blockIdx.x;
    int off = 0;
    for (int i = 0; i < NSCANBLK; ++i)
        off += (i < b) ? bsum[i] : 0;
    const int n = b * SCANB + threadIdx.x;
    if (n < N_NODES) rowstart[n] += off;
    if (b == NSCANBLK - 1 && threadIdx.x == 0)
        rowstart[N_NODES] = off + bsum[NSCANBLK - 1];
}

// pass D: per-cell MFMA; metadata from sequential records; x gathered as bf16;
// basis pre-scaled by 1/deg; msg written to row-sorted slot (full-E buffer)
__global__ __launch_bounds__(256, 2) void bucket_mfma_rec(
    const unsigned short* __restrict__ xbf, const float* __restrict__ weight,
    const unsigned long long* __restrict__ recs,
    const int* __restrict__ cursor,
    const int* __restrict__ rowstart, int* __restrict__ rcur,
    unsigned short* __restrict__ msg)
{
    __shared__ short XS[4][16 * KPAD];

    const int lane = threadIdx.x & 63;
    const int wid  = threadIdx.x >> 6;
    const int cell = blockIdx.x & (NB - 1);
    const int wGlob   = (blockIdx.x >> 4) * 4 + wid;
    const int wStride = (gridDim.x >> 4) * 4;

    const int lo0 = cell & 3, lo1 = cell >> 2;
    const int base = lo0 + 5 * lo1;
    const int offs[4] = {0, 1, 5, 6};
    const int q = lane >> 4;
    const int c = lane & 15;

    // B-fragments: Wstack[k=s*32+q*8+j][o=nt*16+c]
    s8v bfr[4][4];
#pragma unroll
    for (int s = 0; s < 4; ++s) {
        const float* wp = weight + (size_t)(base + offs[s]) * (CIN * COUT);
#pragma unroll
        for (int nt = 0; nt < 4; ++nt) {
            union { unsigned short u[8]; s8v v; } tmp;
#pragma unroll
            for (int j = 0; j < 8; ++j)
                tmp.u[j] = f2bf(wp[(q * 8 + j) * COUT + nt * 16 + c]);
            bfr[s][nt] = tmp.v;
        }
    }

    const unsigned long long* brec = recs + (size_t)cell * BCAP;
    const int cnt    = min(cursor[cell], BCAP);
    const int ntiles = (cnt + 15) >> 4;

    for (int t = wGlob; t < ntiles; t += wStride) {
        const int ebase = t * 16;

        int colv = 0, slotv = 0;
        float b0 = 0.f, b1 = 0.f, b2 = 0.f, b3 = 0.f;
        if (lane < 16 && (ebase + lane) < cnt) {
            const unsigned long long rec = brec[ebase + lane];   // sequential
            const int row = (int)(rec & 0xFFFF);
            colv = (int)((rec >> 16) & 0xFFFF);
            const float f0 = (float)(int)((rec >> 32) & 0xFFFF) * (1.0f / 65536.0f);
            const float f1 = (float)(int)((rec >> 48) & 0xFFFF) * (1.0f / 65536.0f);
            const int rs = rowstart[row], re = rowstart[row + 1];   // L2-resident
            const float invd = 1.0f / (float)max(re - rs, 1);
            b0 = (1.0f - f0) * (1.0f - f1) * invd;
            b1 = f0 * (1.0f - f1) * invd;
            b2 = (1.0f - f0) * f1 * invd;
            b3 = f0 * f1 * invd;
            slotv = rs + atomicAdd(&rcur[row], 1);   // ~16 RMW/addr, cheap
        }

        // gather (bf16, one 64B line/row) + scale + stage X' (16 x 128 bf16)
        {
            const int eg = lane >> 2, part = lane & 3;
            const int  gc = __shfl(colv, eg);
            const float ss0 = __shfl(b0, eg), ss1 = __shfl(b1, eg);
            const float ss2 = __shfl(b2, eg), ss3 = __shfl(b3, eg);
            const float ss[4] = {ss0, ss1, ss2, ss3};
            union { unsigned short u[8]; s8v v; } xin;
            xin.v = *(const s8v*)(xbf + (size_t)gc * CIN + part * 8);
            float xv[8];
#pragma unroll
            for (int j = 0; j < 8; ++j) xv[j] = bf2f(xin.u[j]);
            short* dst = &XS[wid][eg * KPAD + part * 8];
#pragma unroll
            for (int s = 0; s < 4; ++s) {
                union { unsigned short u[8]; s8v v; } tmp;
#pragma unroll
                for (int j = 0; j < 8; ++j)
                    tmp.u[j] = f2bf(ss[s] * xv[j]);
                *(s8v*)(dst + s * 32) = tmp.v;
            }
        }
        __builtin_amdgcn_wave_barrier();

        s8v afr[4];
        {
            const short* ap = &XS[wid][c * KPAD + q * 8];
#pragma unroll
            for (int ks = 0; ks < 4; ++ks)
                afr[ks] = *(const s8v*)(ap + ks * 32);
        }
        __builtin_amdgcn_wave_barrier();

        f4v acc[4];
#pragma unroll
        for (int nt = 0; nt < 4; ++nt) {
            acc[nt] = (f4v){0.f, 0.f, 0.f, 0.f};
#pragma unroll
            for (int ks = 0; ks < 4; ++ks)
                acc[nt] = __builtin_amdgcn_mfma_f32_16x16x32_bf16(
                    afr[ks], bfr[ks][nt], acc[nt], 0, 0, 0);
        }

        // epilogue: acc -> bf16 tile in LDS, coalesced 128B store per edge
#pragma unroll
        for (int r = 0; r < 4; ++r) {
            const int m = q * 4 + r;
#pragma unroll
            for (int nt = 0; nt < 4; ++nt)
                XS[wid][m * 64 + nt * 16 + c] = (short)f2bf(acc[nt][r]);
        }
        __builtin_amdgcn_wave_barrier();
        {
            const int m2 = lane >> 2;
            int slot2 = __shfl(slotv, m2);
            const bool valid2 = (ebase + m2) < cnt;
            slot2 = min(slot2, MSGCAP - 1);   // defensive
            const short* sp = &XS[wid][lane * 16];
            s8v vlo = *(const s8v*)sp;
            s8v vhi = *(const s8v*)(sp + 8);
            if (valid2) {
                unsigned short* dst = msg + (size_t)slot2 * COUT + (lane & 3) * 16;
                *(s8v*)dst = vlo;
                *(s8v*)(dst + 8) = vhi;
            }
        }
        __builtin_amdgcn_wave_barrier();
    }
}

// pass E: per-node segment sum (msg pre-scaled by 1/deg) + root/bias fuse
__global__ __launch_bounds__(256) void gather_sum(
    const unsigned short* __restrict__ msg, const int* __restrict__ rowstart,
    const float* __restrict__ x, const float* __restrict__ root,
    const float* __restrict__ bias, float* __restrict__ out)
{
    const int wave   = (blockIdx.x * blockDim.x + threadIdx.x) >> 6;
    const int lane   = threadIdx.x & 63;
    const int nwaves = (gridDim.x * blockDim.x) >> 6;

    for (int n = wave; n < N_NODES; n += nwaves) {
        const int s  = rowstart[n];
        const int e2 = rowstart[n + 1];
        float acc = 0.f;
#pragma unroll 8
        for (int p = s; p < e2; ++p)
            acc += bf2f(msg[(size_t)p * COUT + lane]);
        const float* xp = x + (size_t)n * CIN;
        float rt = bias[lane];
#pragma unroll
        for (int i = 0; i < CIN; ++i)
            rt += xp[i] * root[i * COUT + lane];
        out[(size_t)n * COUT + lane] = acc + rt;
    }
}

// ================= fallback (R4 atomic) path =================

__global__ __launch_bounds__(256) void count_fb(
    const int* __restrict__ ei, const float* __restrict__ pseudo,
    int* __restrict__ hist, float* __restrict__ deg)
{
    __shared__ int lh[16];
    if (threadIdx.x < 16) lh[threadIdx.x] = 0;
    __syncthreads();
    const int e = blockIdx.x * 256 + threadIdx.x;
    if (e < E_EDGES) {
        int row = min(max(ei[e], 0), N_NODES - 1);
        const float v0 = pseudo[2 * e] * 4.0f, v1 = pseudo[2 * e + 1] * 4.0f;
        const int lo0 = min(max((int)floorf(v0), 0), 3);
        const int lo1 = min(max((int)floorf(v1), 0), 3);
        atomicAdd(&lh[lo0 + 4 * lo1], 1);
        atomicAdd(&deg[row], 1.0f);
    }
    __syncthreads();
    if (threadIdx.x < 16) atomicAdd(&hist[threadIdx.x], lh[threadIdx.x]);
}

__global__ void scan16_fb(const int* __restrict__ hist,
                          int* __restrict__ bstart, int* __restrict__ cursor)
{
    if (threadIdx.x == 0 && blockIdx.x == 0) {
        int acc = 0;
        for (int c = 0; c < 16; ++c) { bstart[c] = acc; cursor[c] = acc; acc += hist[c]; }
    }
}

__global__ __launch_bounds__(256) void scatter_fb(
    const float* __restrict__ pseudo, int* __restrict__ cursor, int* __restrict__ list)
{
    __shared__ int lh[16];
    __shared__ int lbase[16];
    if (threadIdx.x < 16) lh[threadIdx.x] = 0;
    __syncthreads();
    const int e = blockIdx.x * 256 + threadIdx.x;
    int cell = 0, myoff = 0;
    if (e < E_EDGES) {
        const float v0 = pseudo[2 * e] * 4.0f, v1 = pseudo[2 * e + 1] * 4.0f;
        const int lo0 = min(max((int)floorf(v0), 0), 3);
        const int lo1 = min(max((int)floorf(v1), 0), 3);
        cell = lo0 + 4 * lo1;
        myoff = atomicAdd(&lh[cell], 1);
    }
    __syncthreads();
    if (threadIdx.x < 16)
        lbase[threadIdx.x] = atomicAdd(&cursor[threadIdx.x], lh[threadIdx.x]);
    __syncthreads();
    if (e < E_EDGES)
        list[lbase[cell] + myoff] = e;
}

__global__ __launch_bounds__(256, 2) void bucket_mfma_fb(
    const float* __restrict__ x, const int* __restrict__ ei,
    const float* __restrict__ pseudo, const float* __restrict__ weight,
    const int* __restrict__ list, const int* __restrict__ bstart,
    const int* __restrict__ hist, float* __restrict__ out)
{
    __shared__ short XS[4][16 * KPAD];
    const int lane = threadIdx.x & 63;
    const int wid  = threadIdx.x >> 6;
    const int beta = blockIdx.x & 15;
    const int wGlob   = (blockIdx.x >> 4) * 4 + wid;
    const int wStride = (gridDim.x >> 4) * 4;
    const int lo0 = beta & 3, lo1 = beta >> 2;
    const int base = lo0 + 5 * lo1;
    const int offs[4] = {0, 1, 5, 6};
    const int q = lane >> 4, c = lane & 15;

    s8v bfr[4][4];
#pragma unroll
    for (int s = 0; s < 4; ++s) {
        const float* wp = weight + (size_t)(base + offs[s]) * (CIN * COUT);
#pragma unroll
        for (int nt = 0; nt < 4; ++nt) {
            union { unsigned short u[8]; s8v v; } tmp;
#pragma unroll
            for (int j = 0; j < 8; ++j)
                tmp.u[j] = f2bf(wp[(q * 8 + j) * COUT + nt * 16 + c]);
            bfr[s][nt] = tmp.v;
        }
    }
    const int start = bstart[beta], cnt = hist[beta];
    const int ntiles = (cnt + 15) >> 4;

    for (int t = wGlob; t < ntiles; t += wStride) {
        const int ebase = start + t * 16;
        int rowv = 0, colv = 0;
        float b0 = 0.f, b1 = 0.f, b2 = 0.f, b3 = 0.f;
        if (lane < 16 && (t * 16 + lane) < cnt) {
            const int e = list[ebase + lane];
            rowv = min(max(ei[e], 0), N_NODES - 1);
            colv = min(max(ei[E_EDGES + e], 0), N_NODES - 1);
            const float v0 = pseudo[2 * e] * 4.0f, v1 = pseudo[2 * e + 1] * 4.0f;
            const float f0 = v0 - floorf(v0), f1 = v1 - floorf(v1);
            b0 = (1.0f - f0) * (1.0f - f1);
            b1 = f0 * (1.0f - f1);
            b2 = (1.0f - f0) * f1;
            b3 = f0 * f1;
        }
        {
            const int eg = lane >> 2, part = lane & 3;
            const int  gc = __shfl(colv, eg);
            const float ss0 = __shfl(b0, eg), ss1 = __shfl(b1, eg);
            const float ss2 = __shfl(b2, eg), ss3 = __shfl(b3, eg);
            const float ss[4] = {ss0, ss1, ss2, ss3};
            const float* xp = x + (size_t)gc * CIN + part * 8;
            float xv[8];
            *(f4v*)&xv[0] = *(const f4v*)xp;
            *(f4v*)&xv[4] = *(const f4v*)(xp + 4);
            short* dst = &XS[wid][eg * KPAD + part * 8];
#pragma unroll
            for (int s = 0; s < 4; ++s) {
                union { unsigned short u[8]; s8v v; } tmp;
#pragma unroll
                for (int j = 0; j < 8; ++j)
                    tmp.u[j] = f2bf(ss[s] * xv[j]);
                *(s8v*)(dst + s * 32) = tmp.v;
            }
        }
        __builtin_amdgcn_wave_barrier();
        s8v afr[4];
        {
            const short* ap = &XS[wid][c * KPAD + q * 8];
#pragma unroll
            for (int ks = 0; ks < 4; ++ks)
                afr[ks] = *(const s8v*)(ap + ks * 32);
        }
        __builtin_amdgcn_wave_barrier();
        f4v acc[4];
#pragma unroll
        for (int nt = 0; nt < 4; ++nt) {
            acc[nt] = (f4v){0.f, 0.f, 0.f, 0.f};
#pragma unroll
            for (int ks = 0; ks < 4; ++ks)
                acc[nt] = __builtin_amdgcn_mfma_f32_16x16x32_bf16(
                    afr[ks], bfr[ks][nt], acc[nt], 0, 0, 0);
        }
#pragma unroll
        for (int r = 0; r < 4; ++r) {
            const int m = q * 4 + r;
            const int orow = __shfl(rowv, m);
#pragma unroll
            for (int nt = 0; nt < 4; ++nt)
                atomicAdd(&out[(size_t)orow * COUT + nt * 16 + c], acc[nt][r]);
        }
    }
}

__global__ __launch_bounds__(256) void final_fb(
    const float* __restrict__ x, const float* __restrict__ root,
    const float* __restrict__ bias, const float* __restrict__ deg,
    float* __restrict__ out)
{
    const int wave   = (blockIdx.x * blockDim.x + threadIdx.x) >> 6;
    const int lane   = threadIdx.x & 63;
    const int nwaves = (gridDim.x * blockDim.x) >> 6;
    for (int n = wave; n < N_NODES; n += nwaves) {
        const float* xp = x + (size_t)n * CIN;
        float acc = bias[lane];
#pragma unroll
        for (int i = 0; i < CIN; ++i)
            acc += xp[i] * root[i * COUT + lane];
        float dg = deg[n];
        dg = dg > 1.0f ? dg : 1.0f;
        const size_t idx = (size_t)n * COUT + lane;
        out[idx] = out[idx] / dg + acc;
    }
}

extern "C" void kernel_launch(void* const* d_in, const int* in_sizes, int n_in,
                              void* d_out, int out_size, void* d_ws, size_t ws_size,
                              hipStream_t stream) {
    const float* x      = (const float*)d_in[0];
    const int*   ei     = (const int*)d_in[1];
    const float* pseudo = (const float*)d_in[2];
    const float* weight = (const float*)d_in[3];
    const float* root   = (const float*)d_in[4];
    const float* bias   = (const float*)d_in[5];
    float* out = (float*)d_out;

    // ws layout (int elements)
    int* wsI = (int*)d_ws;
    int* cursor16 = wsI;                         // 16 (+16 pad)
    int* degi4    = wsI + 32;                    // 4 x 50000
    int* rcur     = wsI + 200032;                // 50000
    int* rowstart = wsI + 250032;                // 50001 (+15 pad)
    int* bsum     = wsI + 300048;                // 64
    // 300112 ints = 1200448 B, 8B-aligned
    unsigned long long* recs = (unsigned long long*)(wsI + 300112);  // 6.91 MB
    unsigned short* xbf = (unsigned short*)((char*)d_ws + 1200448
                        + (size_t)NB * BCAP * 8);                    // 3.2 MB
    unsigned short* msg = (unsigned short*)((char*)xbf
                        + (size_t)N_NODES * CIN * 2);                // 102.4 MB
    const size_t needed = 1200448 + (size_t)NB * BCAP * 8
                        + (size_t)N_NODES * CIN * 2
                        + (size_t)MSGCAP * COUT * 2;  // ~114 MB

    if (ws_size >= needed) {
        hipMemsetAsync(d_ws, 0, (size_t)250032 * 4, stream);  // cursor+degi4+rcur
        x2bf_kernel<<<(N_NODES * CIN / 4 + 255) / 256, 256, 0, stream>>>(x, xbf);
        build_recs <<<BBLK, 256, 0, stream>>>(ei, pseudo, cursor16, recs, degi4);
        scan_blocks<<<NSCANBLK, 1024, 0, stream>>>(degi4, rowstart, bsum);
        scan_finish<<<NSCANBLK, 1024, 0, stream>>>(rowstart, bsum);
        bucket_mfma_rec<<<16 * 128, 256, 0, stream>>>(
            xbf, weight, recs, cursor16, rowstart, rcur, msg);
        gather_sum<<<4096, 256, 0, stream>>>(msg, rowstart, x, root, bias, out);
    } else {
        // R4 fallback layout
        char* w = (char*)d_ws;
        float* degF   = (float*)w;
        int*   histF  = (int*)(w + 200064);
        int*   bstF   = (int*)(w + 200128);
        int*   curF   = (int*)(w + 200192);
        int*   listF  = (int*)(w + 200256);
        const int eblocks = (E_EDGES + 255) / 256;

        hipMemsetAsync(out, 0, sizeof(float) * (size_t)N_NODES * COUT, stream);
        hipMemsetAsync(degF, 0, sizeof(float) * (size_t)N_NODES, stream);
        hipMemsetAsync(histF, 0, 192, stream);

        count_fb      <<<eblocks, 256, 0, stream>>>(ei, pseudo, histF, degF);
        scan16_fb     <<<1, 64, 0, stream>>>(histF, bstF, curF);
        scatter_fb    <<<eblocks, 256, 0, stream>>>(pseudo, curF, listF);
        bucket_mfma_fb<<<16 * 64, 256, 0, stream>>>(x, ei, pseudo, weight, listF,
                                                    bstF, histF, out);
        final_fb      <<<1024, 256, 0, stream>>>(x, root, bias, degF, out);
    }
}